// Round 21
// baseline (157.013 us; speedup 1.0000x reference)
//
#include <hip/hip_runtime.h>
#include <hip/hip_fp16.h>
#include <math.h>

#define F_IN   256
#define C1     128   // H1*D1
#define H1N    4
#define D2N    64

#define SCAN_T    256
#define SCAN_TILE 512   // 2 elements per thread

#define BK2 32          // gemm2 K-tile

#define NBLK_P 256      // partition blocks
#define NBUK_MAX 256    // max coarse buckets (dst >> 8)

typedef __attribute__((ext_vector_type(8))) _Float16 f16x8;
typedef __attribute__((ext_vector_type(4))) float    f32x4;

// ---------------- W1 transpose to fp16: W1T[c][k] = (half)W1[k][c] ----------------
__global__ void w1_transpose(const float* __restrict__ W1, __half* __restrict__ W1T) {
    int c = blockIdx.x;                       // 0..127
    for (int k = threadIdx.x; k < F_IN; k += blockDim.x)
        W1T[(size_t)c * F_IN + k] = __float2half(W1[(size_t)k * C1 + c]);
}

// ---------------- fused: layer-1 MFMA GEMM (blocks < ngemm) + bucket histogram ----------------
// GEMM: whole 64x256 x-tile in LDS (ONE barrier), B-fragments register double-buffered
// so each K-step's 8 W1T loads issue while the previous step's MFMAs execute —
// breaks the load->waitcnt->mfma serialization seen as 93% memory stall in R20.
__global__ __launch_bounds__(256) void gemm1_hist_kernel(
        const float* __restrict__ x, const __half* __restrict__ W1T,
        const float* __restrict__ attS, const float* __restrict__ attD,
        __half* __restrict__ hx1h, float* __restrict__ as1, float* __restrict__ ad1,
        int N,
        const int* __restrict__ dst, int* __restrict__ bcounts,
        int E, int chunk, int nbuk, int ngemm) {
    if ((int)blockIdx.x >= ngemm) {
        __shared__ int h[NBUK_MAX];
        int b = blockIdx.x - ngemm;           // 0..NBLK_P-1
        for (int t = threadIdx.x; t < nbuk; t += blockDim.x) h[t] = 0;
        __syncthreads();
        int lo = b * chunk, hi = min(lo + chunk, E);
        for (int i = lo + threadIdx.x; i < hi; i += blockDim.x)
            atomicAdd(&h[dst[i] >> 8], 1);                 // LDS atomic
        __syncthreads();
        for (int t = threadIdx.x; t < nbuk; t += blockDim.x)
            bcounts[(size_t)t * NBLK_P + b] = h[t];
        return;
    }

    __shared__ __half xh[64][264];  // whole tile; 528B row stride (16B-aligned, 2-way banks)

    int tid = threadIdx.x;
    int wv  = tid >> 6;             // wave 0..3
    int l   = tid & 63;
    int n0  = blockIdx.x * 64;

    // ---- stage whole x-tile (contiguous 16384 floats) as fp16, coalesced ----
#pragma unroll
    for (int it = 0; it < 8; ++it) {
        int f   = (it * 256 + tid) * 8;        // flat float index, 8-float chunk
        int row = f >> 8;                      // 0..63
        int k   = f & 255;
        int grow = n0 + row; if (grow >= N) grow = N - 1;
        const float* sp = x + (size_t)grow * F_IN + k;
        float4 a0 = *(const float4*)(sp);
        float4 a1 = *(const float4*)(sp + 4);
        __half2* dp = (__half2*)&xh[row][k];
        dp[0] = __floats2half2_rn(a0.x, a0.y);
        dp[1] = __floats2half2_rn(a0.z, a0.w);
        dp[2] = __floats2half2_rn(a1.x, a1.y);
        dp[3] = __floats2half2_rn(a1.z, a1.w);
    }

    int arow = wv * 16 + (l & 15);        // A row within block tile
    int akk  = (l >> 4) * 8;              // A k-run
    int bcol = l & 15;                    // B col within 16-col tile
    int bkk  = (l >> 4) * 8;              // B k-run
    const __half* wbase = W1T + (size_t)bcol * F_IN + bkk;

    f32x4 acc[8];
#pragma unroll
    for (int t = 0; t < 8; ++t) acc[t] = (f32x4){0.f, 0.f, 0.f, 0.f};

    // register double-buffer for B fragments
    f16x8 bfr[2][8];
#pragma unroll
    for (int t = 0; t < 8; ++t)
        bfr[0][t] = *reinterpret_cast<const f16x8*>(wbase + (size_t)(16 * t) * F_IN);

    __syncthreads();                           // the ONLY barrier

#pragma unroll
    for (int s = 0; s < 8; ++s) {
        int k0  = s * 32;
        int cur = s & 1, nxt = cur ^ 1;
        if (s < 7) {
#pragma unroll
            for (int t = 0; t < 8; ++t)
                bfr[nxt][t] = *reinterpret_cast<const f16x8*>(
                    wbase + (size_t)(16 * t) * F_IN + k0 + 32);
        }
        f16x8 af = *reinterpret_cast<const f16x8*>(&xh[arow][k0 + akk]);
#pragma unroll
        for (int t = 0; t < 8; ++t)
            acc[t] = __builtin_amdgcn_mfma_f32_16x16x32_f16(af, bfr[cur][t], acc[t], 0, 0, 0);
    }

    // epilogue: D layout col = l&15, row = 4*(l>>4)+r
    float aS[8], aD[8];
#pragma unroll
    for (int t = 0; t < 8; ++t) {
        aS[t] = attS[16 * t + bcol];
        aD[t] = attD[16 * t + bcol];
    }
#pragma unroll
    for (int r = 0; r < 4; ++r) {
        int n = n0 + wv * 16 + 4 * (l >> 4) + r;
        float ts[4], td[4];
#pragma unroll
        for (int h = 0; h < 4; ++h) {
            ts[h] = acc[2 * h][r] * aS[2 * h] + acc[2 * h + 1][r] * aS[2 * h + 1];
            td[h] = acc[2 * h][r] * aD[2 * h] + acc[2 * h + 1][r] * aD[2 * h + 1];
        }
#pragma unroll
        for (int off = 1; off <= 8; off <<= 1)
#pragma unroll
            for (int h = 0; h < 4; ++h) {
                ts[h] += __shfl_xor(ts[h], off, 64);
                td[h] += __shfl_xor(td[h], off, 64);
            }
        if (n < N) {
#pragma unroll
            for (int t = 0; t < 8; ++t)
                hx1h[(size_t)n * C1 + 16 * t + bcol] = __float2half(acc[t][r]);
            if (bcol == 0) {
#pragma unroll
                for (int h = 0; h < 4; ++h) {
                    as1[n * H1N + h] = ts[h];
                    ad1[n * H1N + h] = td[h];
                }
            }
        }
    }
}

// ---------------- CSR build pass C: partition edges into bucket order ----------------
__global__ void part_scatter(const int* __restrict__ src, const int* __restrict__ dst,
                             const int* __restrict__ bbase, int2* __restrict__ pedge,
                             int E, int chunk, int nbuk) {
    __shared__ int cur[NBUK_MAX];
    for (int t = threadIdx.x; t < nbuk; t += blockDim.x)
        cur[t] = bbase[(size_t)t * NBLK_P + blockIdx.x];
    __syncthreads();
    int lo = blockIdx.x * chunk, hi = min(lo + chunk, E);
    for (int i = lo + threadIdx.x; i < hi; i += blockDim.x) {
        int d = dst[i];
        int p = atomicAdd(&cur[d >> 8], 1);            // LDS atomic
        pedge[p] = make_int2(src[i], d);
    }
}

// ---------------- CSR build pass D: per-bucket fine CSR (256 nodes/bucket) ----------------
__global__ __launch_bounds__(256) void part_csr(
        const int2* __restrict__ pedge, const int* __restrict__ bbase,
        int* __restrict__ offsets, int* __restrict__ edge_src,
        int N, int E, int nbuk) {
    __shared__ int fcnt[256];
    __shared__ int fsc[256];
    int b = blockIdx.x;
    int t = threadIdx.x;
    int ebeg = bbase[(size_t)b * NBLK_P];
    int eend = (b + 1 < nbuk) ? bbase[(size_t)(b + 1) * NBLK_P] : E;
    int nbase = b << 8;
    fcnt[t] = 0;
    __syncthreads();
    for (int i = ebeg + t; i < eend; i += 256)
        atomicAdd(&fcnt[pedge[i].y - nbase], 1);       // LDS atomic
    __syncthreads();
    int v = fcnt[t];
    fsc[t] = v;
    __syncthreads();
    for (int off = 1; off < 256; off <<= 1) {
        int u = (t >= off) ? fsc[t - off] : 0;
        __syncthreads();
        fsc[t] += u;
        __syncthreads();
    }
    int goff = ebeg + fsc[t] - v;                      // global CSR start of node nbase+t
    int node = nbase + t;
    if (node < N) offsets[node] = goff;
    if (b == nbuk - 1 && t == 0) offsets[N] = E;
    __syncthreads();
    fcnt[t] = goff;                                    // reuse as cursor
    __syncthreads();
    for (int i = ebeg + t; i < eend; i += 256) {
        int2 e = pedge[i];
        int p = atomicAdd(&fcnt[e.y - nbase], 1);      // LDS atomic
        edge_src[p] = e.x;
    }
}

// ---------------- scan: generic hierarchical exclusive scan ----------------
__global__ void scan_partial(const int* __restrict__ counts, int* __restrict__ tilesums, int N) {
    __shared__ int red[SCAN_T];
    int t  = threadIdx.x;
    int i0 = blockIdx.x * SCAN_TILE + 2 * t;
    int s = 0;
    if (i0     < N) s += counts[i0];
    if (i0 + 1 < N) s += counts[i0 + 1];
    red[t] = s;
    __syncthreads();
    for (int off = SCAN_T / 2; off > 0; off >>= 1) {
        if (t < off) red[t] += red[t + off];
        __syncthreads();
    }
    if (t == 0) tilesums[blockIdx.x] = red[0];
}

__global__ void scan_tops(const int* __restrict__ tilesums, int* __restrict__ tilebase, int ntiles) {
    __shared__ int sh[SCAN_T];
    int t = threadIdx.x;
    int v = (t < ntiles) ? tilesums[t] : 0;
    sh[t] = v;
    __syncthreads();
    for (int off = 1; off < SCAN_T; off <<= 1) {
        int u = (t >= off) ? sh[t - off] : 0;
        __syncthreads();
        sh[t] += u;
        __syncthreads();
    }
    tilebase[t] = sh[t] - v;
}

__global__ void scan_final(const int* __restrict__ counts, const int* __restrict__ tilebase,
                           int* __restrict__ base, int N, int E) {
    __shared__ int sh[SCAN_T];
    int t  = threadIdx.x;
    int i0 = blockIdx.x * SCAN_TILE + 2 * t;
    int a   = (i0     < N) ? counts[i0]     : 0;
    int b   = (i0 + 1 < N) ? counts[i0 + 1] : 0;
    int tot = a + b;
    sh[t] = tot;
    __syncthreads();
    for (int off = 1; off < SCAN_T; off <<= 1) {
        int u = (t >= off) ? sh[t - off] : 0;
        __syncthreads();
        sh[t] += u;
        __syncthreads();
    }
    int excl = sh[t] - tot + tilebase[blockIdx.x];
    if (i0 < N)     base[i0]     = excl;
    if (i0 + 1 < N) base[i0 + 1] = excl + a;
    if (blockIdx.x == 0 && t == 0) base[N] = E;
}

// ---------------- layer 1 aggregate: no-max softmax, fp16 gather, fp16 x1 out ----------------
__global__ void agg1_kernel(const int* __restrict__ edge_src, const int* __restrict__ offsets,
                            const float* __restrict__ as1, const float* __restrict__ ad1,
                            const __half* __restrict__ hx1h, const float* __restrict__ b1,
                            __half* __restrict__ x1h, int N) {
    __shared__ int   ssh[4][64];
    __shared__ float esh[4][64][4];
    int wid  = threadIdx.x >> 6;
    int n    = (blockIdx.x * blockDim.x + threadIdx.x) >> 6;
    int lane = threadIdx.x & 63;
    if (n >= N) return;
    int hsel = lane >> 4;                    // head of cols (2l, 2l+1)
    const float4 ad4 = *(const float4*)(ad1 + 4 * n);
    int beg = offsets[n], end = offsets[n + 1];

    float den[4] = {0.f, 0.f, 0.f, 0.f};
    float acc0 = 0.f, acc1 = 0.f;

    for (int cb = beg; cb < end; cb += 64) {
        int j = cb + lane;
        bool valid = j < end;
        int s = valid ? edge_src[j] : 0;
        float e0 = 0.f, e1 = 0.f, e2 = 0.f, e3 = 0.f;
        if (valid) {
            const float4 a4 = *(const float4*)(as1 + 4 * s);
            float v0 = a4.x + ad4.x, v1 = a4.y + ad4.y;
            float v2 = a4.z + ad4.z, v3 = a4.w + ad4.w;
            v0 = v0 > 0.f ? v0 : 0.2f * v0;
            v1 = v1 > 0.f ? v1 : 0.2f * v1;
            v2 = v2 > 0.f ? v2 : 0.2f * v2;
            v3 = v3 > 0.f ? v3 : 0.2f * v3;
            e0 = __expf(v0); e1 = __expf(v1);
            e2 = __expf(v2); e3 = __expf(v3);
            den[0] += e0; den[1] += e1; den[2] += e2; den[3] += e3;
        }
        ssh[wid][lane] = s;
        *(float4*)&esh[wid][lane][0] = make_float4(e0, e1, e2, e3);

        int cnt = min(64, end - cb);
#pragma unroll 4
        for (int jj = 0; jj < cnt; ++jj) {
            int   sj = ssh[wid][jj];
            float w  = esh[wid][jj][hsel];
            const __half2* hr = (const __half2*)(hx1h + (size_t)sj * C1);
            float2 vf = __half22float2(hr[lane]);
            acc0 += w * vf.x;
            acc1 += w * vf.y;
        }
    }

#pragma unroll
    for (int off = 32; off > 0; off >>= 1)
#pragma unroll
        for (int h = 0; h < 4; ++h) den[h] += __shfl_xor(den[h], off, 64);

    float d = lane < 16 ? den[0] : lane < 32 ? den[1] : lane < 48 ? den[2] : den[3];
    float inv = 1.f / (d + 1e-16f);
    float2 bv = *(const float2*)(b1 + 2 * lane);
    float o0 = acc0 * inv + bv.x;
    float o1 = acc1 * inv + bv.y;
    o0 = o0 > 0.f ? o0 : (__expf(o0) - 1.f);   // ELU
    o1 = o1 > 0.f ? o1 : (__expf(o1) - 1.f);
    *(__half2*)&x1h[(size_t)n * C1 + 2 * lane] = __floats2half2_rn(o0, o1);
}

// ---------------- layer 2 GEMM: hx2 = x1 @ W2 (+ logits); fp16 in, fp16 out ----------------
__global__ __launch_bounds__(256) void gemm2_kernel(
        const __half* __restrict__ x1h, const float* __restrict__ W2,
        const float* __restrict__ attS, const float* __restrict__ attD,
        __half* __restrict__ hx2h, float* __restrict__ as2, float* __restrict__ ad2,
        int N) {
    __shared__ float xT[BK2][64 + 4];
    __shared__ float ws2[BK2][D2N];

    int tid = threadIdx.x;
    int tx  = tid & 15;
    int ty  = tid >> 4;
    int n0  = blockIdx.x * 64;

    float acc[4][4];
#pragma unroll
    for (int r = 0; r < 4; ++r)
#pragma unroll
        for (int c = 0; c < 4; ++c) acc[r][c] = 0.f;

    int lr = tid >> 2;                 // 0..63
    int lk = (tid & 3) * 8;            // 0,8,16,24 (8 halves = 16B)
    int xrow = n0 + lr; if (xrow >= N) xrow = N - 1;
    const __half* xptr = x1h + (size_t)xrow * C1;
    int kw = tid >> 4;
    int cw = tx * 4;

    for (int k0 = 0; k0 < C1; k0 += BK2) {
        f16x8 a = *reinterpret_cast<const f16x8*>(xptr + k0 + lk);
        float4 w0 = *(const float4*)(W2 + (size_t)(k0 + kw     ) * D2N + cw);
        float4 w1 = *(const float4*)(W2 + (size_t)(k0 + kw + 16) * D2N + cw);
        __syncthreads();
#pragma unroll
        for (int j = 0; j < 8; ++j) xT[lk + j][lr] = (float)a[j];
        *(float4*)&ws2[kw     ][cw] = w0;
        *(float4*)&ws2[kw + 16][cw] = w1;
        __syncthreads();
#pragma unroll
        for (int k = 0; k < BK2; ++k) {
            float4 xa = *(const float4*)&xT[k][ty * 4];
            float4 wv = *(const float4*)&ws2[k][tx * 4];
            float xr[4] = {xa.x, xa.y, xa.z, xa.w};
            float wc[4] = {wv.x, wv.y, wv.z, wv.w};
#pragma unroll
            for (int r = 0; r < 4; ++r)
#pragma unroll
                for (int c = 0; c < 4; ++c) acc[r][c] += xr[r] * wc[c];
        }
    }

    const float4 asv = *(const float4*)(attS + tx * 4);
    const float4 adv = *(const float4*)(attD + tx * 4);
#pragma unroll
    for (int r = 0; r < 4; ++r) {
        int n = n0 + ty * 4 + r;
        float ts = acc[r][0] * asv.x + acc[r][1] * asv.y + acc[r][2] * asv.z + acc[r][3] * asv.w;
        float td = acc[r][0] * adv.x + acc[r][1] * adv.y + acc[r][2] * adv.z + acc[r][3] * adv.w;
        ts += __shfl_xor(ts, 1); td += __shfl_xor(td, 1);
        ts += __shfl_xor(ts, 2); td += __shfl_xor(td, 2);
        ts += __shfl_xor(ts, 4); td += __shfl_xor(td, 4);
        ts += __shfl_xor(ts, 8); td += __shfl_xor(td, 8);
        if (n < N) {
            *(__half2*)&hx2h[(size_t)n * D2N + tx * 4]     = __floats2half2_rn(acc[r][0], acc[r][1]);
            *(__half2*)&hx2h[(size_t)n * D2N + tx * 4 + 2] = __floats2half2_rn(acc[r][2], acc[r][3]);
            if (tx == 0) { as2[n] = ts; ad2[n] = td; }
        }
    }
}

// ---------------- layer 2 aggregate: no-max softmax, fp16 gather, last num_new nodes ----------------
__global__ void agg2_kernel(const int* __restrict__ edge_src, const int* __restrict__ offsets,
                            const float* __restrict__ as2, const float* __restrict__ ad2,
                            const __half* __restrict__ hx2h, const float* __restrict__ b2,
                            float* __restrict__ out, int N, int num_new) {
    __shared__ int   ssh[4][64];
    __shared__ float esh[4][64];
    int wid  = threadIdx.x >> 6;
    int w    = (blockIdx.x * blockDim.x + threadIdx.x) >> 6;
    int lane = threadIdx.x & 63;
    if (w >= num_new) return;
    int n = N - num_new + w;
    float adn = ad2[n];
    int beg = offsets[n], end = offsets[n + 1];

    float den = 0.f, acc = 0.f;
    for (int cb = beg; cb < end; cb += 64) {
        int j = cb + lane;
        bool valid = j < end;
        int s = valid ? edge_src[j] : 0;
        float e = 0.f;
        if (valid) {
            float v = as2[s] + adn;
            v = v > 0.f ? v : 0.2f * v;
            e = __expf(v);
            den += e;
        }
        ssh[wid][lane] = s;
        esh[wid][lane] = e;

        int cnt = min(64, end - cb);
#pragma unroll 4
        for (int jj = 0; jj < cnt; ++jj) {
            int   sj = ssh[wid][jj];
            float wj = esh[wid][jj];
            acc += wj * __half2float(hx2h[(size_t)sj * D2N + lane]);
        }
    }
#pragma unroll
    for (int off = 32; off > 0; off >>= 1) den += __shfl_xor(den, off, 64);
    out[(size_t)w * D2N + lane] = acc / (den + 1e-16f) + b2[lane];
}

// ---------------- launch ----------------
extern "C" void kernel_launch(void* const* d_in, const int* in_sizes, int n_in,
                              void* d_out, int out_size, void* d_ws, size_t ws_size,
                              hipStream_t stream) {
    const float* x      = (const float*)d_in[0];
    const int*   src    = (const int*)d_in[1];
    const int*   dst    = (const int*)d_in[2];
    const float* W1     = (const float*)d_in[3];
    const float* attS1  = (const float*)d_in[4];
    const float* attD1  = (const float*)d_in[5];
    const float* b1     = (const float*)d_in[6];
    const float* W2     = (const float*)d_in[7];
    const float* attS2  = (const float*)d_in[8];
    const float* attD2  = (const float*)d_in[9];
    const float* b2     = (const float*)d_in[10];

    const int N = in_sizes[0] / F_IN;   // 50000
    const int E = in_sizes[1];          // 1000000
    const int num_new = out_size / D2N; // 10000
    const int ngemm  = (N + 63) / 64;                     // 782
    const int nbuk   = (N + 255) >> 8;                    // 196
    const int M      = nbuk * NBLK_P;                     // 50176
    const int ntilesM = (M + SCAN_TILE - 1) / SCAN_TILE;  // 98
    const int chunk  = (E + NBLK_P - 1) / NBLK_P;         // 3907

    // workspace carve-up
    __half* hx1h = (__half*)d_ws;                        // N*128 halves
    __half* x1h  = hx1h + (size_t)N * C1;                // N*128 halves
    __half* hx2h = x1h  + (size_t)N * C1;                // N*64 halves
    float* as1 = (float*)(hx2h + (size_t)N * D2N);       // N*4
    float* ad1 = as1 + (size_t)N * H1N;                  // N*4
    float* as2 = ad1 + (size_t)N * H1N;                  // N
    float* ad2 = as2 + N;                                // N
    int* bcounts  = (int*)(ad2 + N);                     // M
    int* bbase    = bcounts + M;                         // M+1
    int* offsets  = bbase + M + 1;                       // N+1
    int* tilesums = offsets + N + 1;                     // 256
    int* tilebase = tilesums + 256;                      // 256
    int* edge_src = tilebase + 256;                      // E
    int2* pedge   = (int2*)(edge_src + E);               // E int2
    __half* W1T   = (__half*)(pedge + E);                // 128*256 halves

    float* out = (float*)d_out;

    hipLaunchKernelGGL(w1_transpose, dim3(C1), dim3(256), 0, stream, W1, W1T);
    hipLaunchKernelGGL(gemm1_hist_kernel, dim3(ngemm + NBLK_P), dim3(256), 0, stream,
                       x, W1T, attS1, attD1, hx1h, as1, ad1, N,
                       dst, bcounts, E, chunk, nbuk, ngemm);
    hipLaunchKernelGGL(scan_partial, dim3(ntilesM), dim3(SCAN_T), 0, stream, bcounts, tilesums, M);
    hipLaunchKernelGGL(scan_tops, dim3(1), dim3(SCAN_T), 0, stream, tilesums, tilebase, ntilesM);
    hipLaunchKernelGGL(scan_final, dim3(ntilesM), dim3(SCAN_T), 0, stream,
                       bcounts, tilebase, bbase, M, E);
    hipLaunchKernelGGL(part_scatter, dim3(NBLK_P), dim3(256), 0, stream,
                       src, dst, bbase, pedge, E, chunk, nbuk);
    hipLaunchKernelGGL(part_csr, dim3(nbuk), dim3(256), 0, stream,
                       pedge, bbase, offsets, edge_src, N, E, nbuk);
    hipLaunchKernelGGL(agg1_kernel, dim3((N + 3) / 4), dim3(256), 0, stream,
                       edge_src, offsets, as1, ad1, hx1h, b1, x1h, N);
    hipLaunchKernelGGL(gemm2_kernel, dim3((N + 63) / 64), dim3(256), 0, stream,
                       x1h, W2, attS2, attD2, hx2h, as2, ad2, N);
    hipLaunchKernelGGL(agg2_kernel, dim3((num_new + 3) / 4), dim3(256), 0, stream,
                       edge_src, offsets, as2, ad2, hx2h, b2, out, N, num_new);
}

// Round 22
// 145.913 us; speedup vs baseline: 1.0761x; 1.0761x over previous
//
#include <hip/hip_runtime.h>
#include <hip/hip_fp16.h>
#include <math.h>

#define F_IN   256
#define C1     128   // H1*D1
#define H1N    4
#define D2N    64

#define SCAN_T    256
#define SCAN_TILE 512   // 2 elements per thread

#define BK2 32          // gemm2 K-tile

#define NBLK_P 256      // partition blocks
#define NBUK_MAX 256    // max coarse buckets (dst >> 8)

typedef __attribute__((ext_vector_type(8))) _Float16 f16x8;
typedef __attribute__((ext_vector_type(4))) float    f32x4;

// ---------------- prep: W1 transpose (blocks<128) + bucket histogram (rest) ----------------
__global__ void prep_kernel(const float* __restrict__ W1, __half* __restrict__ W1T,
                            const int* __restrict__ dst, int* __restrict__ bcounts,
                            int E, int chunk, int nbuk) {
    if ((int)blockIdx.x < C1) {
        int c = blockIdx.x;
        for (int k = threadIdx.x; k < F_IN; k += blockDim.x)
            W1T[(size_t)c * F_IN + k] = __float2half(W1[(size_t)k * C1 + c]);
        return;
    }
    __shared__ int h[NBUK_MAX];
    int b = blockIdx.x - C1;                  // 0..NBLK_P-1
    for (int t = threadIdx.x; t < nbuk; t += blockDim.x) h[t] = 0;
    __syncthreads();
    int lo = b * chunk, hi = min(lo + chunk, E);
    for (int i = lo + threadIdx.x; i < hi; i += blockDim.x)
        atomicAdd(&h[dst[i] >> 8], 1);                 // LDS atomic
    __syncthreads();
    for (int t = threadIdx.x; t < nbuk; t += blockDim.x)
        bcounts[(size_t)t * NBLK_P + b] = h[t];
}

// ---------------- fused: layer-1 MFMA GEMM (blocks < ngemm) + edge partition (rest) ----------------
// gemm (R20 structure, known-good) and part_scatter are independent until agg1 —
// fusing hides the scatter's ~15-20us under gemm1's idle machine.
__global__ __launch_bounds__(256) void gemm1_scatter_kernel(
        const float* __restrict__ x, const __half* __restrict__ W1T,
        const float* __restrict__ attS, const float* __restrict__ attD,
        __half* __restrict__ hx1h, float* __restrict__ as1, float* __restrict__ ad1,
        int N,
        const int* __restrict__ src, const int* __restrict__ dst,
        const int* __restrict__ bbase, int2* __restrict__ pedge,
        int E, int chunk, int nbuk, int ngemm) {
    if ((int)blockIdx.x >= ngemm) {
        __shared__ int cur[NBUK_MAX];
        int b = blockIdx.x - ngemm;           // 0..NBLK_P-1
        for (int t = threadIdx.x; t < nbuk; t += blockDim.x)
            cur[t] = bbase[(size_t)t * NBLK_P + b];
        __syncthreads();
        int lo = b * chunk, hi = min(lo + chunk, E);
        for (int i = lo + threadIdx.x; i < hi; i += blockDim.x) {
            int d = dst[i];
            int p = atomicAdd(&cur[d >> 8], 1);        // LDS atomic
            pedge[p] = make_int2(src[i], d);
        }
        return;
    }

    __shared__ __half xh[64][40];   // 80B row stride: 16B-aligned, 2-way banks max

    int tid = threadIdx.x;
    int wv  = tid >> 6;             // wave 0..3
    int l   = tid & 63;
    int n0  = blockIdx.x * 64;

    f32x4 acc[8];
#pragma unroll
    for (int t = 0; t < 8; ++t) acc[t] = (f32x4){0.f, 0.f, 0.f, 0.f};

    int srow = tid >> 2;                  // 0..63
    int skg  = (tid & 3) * 8;             // 0,8,16,24
    int xrow = n0 + srow; if (xrow >= N) xrow = N - 1;   // clamp (stores guarded)
    const float* xptr = x + (size_t)xrow * F_IN;

    int arow = wv * 16 + (l & 15);        // A row within block tile
    int akk  = (l >> 4) * 8;              // A k-run
    int bcol = l & 15;                    // B col within 16-col tile
    int bkk  = (l >> 4) * 8;              // B k-run

    // prologue: load K-step 0
    float4 a0 = *(const float4*)(xptr + skg);
    float4 a1 = *(const float4*)(xptr + skg + 4);

    for (int s = 0; s < 8; ++s) {
        int k0 = s * 32;
        __syncthreads();                  // previous tile consumed
        __half2* dp = (__half2*)&xh[srow][skg];
        dp[0] = __floats2half2_rn(a0.x, a0.y);
        dp[1] = __floats2half2_rn(a0.z, a0.w);
        dp[2] = __floats2half2_rn(a1.x, a1.y);
        dp[3] = __floats2half2_rn(a1.z, a1.w);
        __syncthreads();
        if (s < 7) {                      // prefetch next K-step
            a0 = *(const float4*)(xptr + k0 + 32 + skg);
            a1 = *(const float4*)(xptr + k0 + 32 + skg + 4);
        }
        f16x8 af = *reinterpret_cast<const f16x8*>(&xh[arow][akk]);
#pragma unroll
        for (int t = 0; t < 8; ++t) {
            f16x8 bf = *reinterpret_cast<const f16x8*>(
                W1T + (size_t)(16 * t + bcol) * F_IN + k0 + bkk);
            acc[t] = __builtin_amdgcn_mfma_f32_16x16x32_f16(af, bf, acc[t], 0, 0, 0);
        }
    }

    // epilogue: D layout col = l&15, row = 4*(l>>4)+r
    float aS[8], aD[8];
#pragma unroll
    for (int t = 0; t < 8; ++t) {
        aS[t] = attS[16 * t + bcol];
        aD[t] = attD[16 * t + bcol];
    }
#pragma unroll
    for (int r = 0; r < 4; ++r) {
        int n = n0 + wv * 16 + 4 * (l >> 4) + r;
        float ts[4], td[4];
#pragma unroll
        for (int h = 0; h < 4; ++h) {
            ts[h] = acc[2 * h][r] * aS[2 * h] + acc[2 * h + 1][r] * aS[2 * h + 1];
            td[h] = acc[2 * h][r] * aD[2 * h] + acc[2 * h + 1][r] * aD[2 * h + 1];
        }
#pragma unroll
        for (int off = 1; off <= 8; off <<= 1)
#pragma unroll
            for (int h = 0; h < 4; ++h) {
                ts[h] += __shfl_xor(ts[h], off, 64);
                td[h] += __shfl_xor(td[h], off, 64);
            }
        if (n < N) {
#pragma unroll
            for (int t = 0; t < 8; ++t)
                hx1h[(size_t)n * C1 + 16 * t + bcol] = __float2half(acc[t][r]);
            if (bcol == 0) {
#pragma unroll
                for (int h = 0; h < 4; ++h) {
                    as1[n * H1N + h] = ts[h];
                    ad1[n * H1N + h] = td[h];
                }
            }
        }
    }
}

// ---------------- CSR build pass D: per-bucket fine CSR (256 nodes/bucket) ----------------
__global__ __launch_bounds__(256) void part_csr(
        const int2* __restrict__ pedge, const int* __restrict__ bbase,
        int* __restrict__ offsets, int* __restrict__ edge_src,
        int N, int E, int nbuk) {
    __shared__ int fcnt[256];
    __shared__ int fsc[256];
    int b = blockIdx.x;
    int t = threadIdx.x;
    int ebeg = bbase[(size_t)b * NBLK_P];
    int eend = (b + 1 < nbuk) ? bbase[(size_t)(b + 1) * NBLK_P] : E;
    int nbase = b << 8;
    fcnt[t] = 0;
    __syncthreads();
    for (int i = ebeg + t; i < eend; i += 256)
        atomicAdd(&fcnt[pedge[i].y - nbase], 1);       // LDS atomic
    __syncthreads();
    int v = fcnt[t];
    fsc[t] = v;
    __syncthreads();
    for (int off = 1; off < 256; off <<= 1) {
        int u = (t >= off) ? fsc[t - off] : 0;
        __syncthreads();
        fsc[t] += u;
        __syncthreads();
    }
    int goff = ebeg + fsc[t] - v;                      // global CSR start of node nbase+t
    int node = nbase + t;
    if (node < N) offsets[node] = goff;
    if (b == nbuk - 1 && t == 0) offsets[N] = E;
    __syncthreads();
    fcnt[t] = goff;                                    // reuse as cursor
    __syncthreads();
    for (int i = ebeg + t; i < eend; i += 256) {
        int2 e = pedge[i];
        int p = atomicAdd(&fcnt[e.y - nbase], 1);      // LDS atomic
        edge_src[p] = e.x;
    }
}

// ---------------- scan: generic hierarchical exclusive scan ----------------
__global__ void scan_partial(const int* __restrict__ counts, int* __restrict__ tilesums, int N) {
    __shared__ int red[SCAN_T];
    int t  = threadIdx.x;
    int i0 = blockIdx.x * SCAN_TILE + 2 * t;
    int s = 0;
    if (i0     < N) s += counts[i0];
    if (i0 + 1 < N) s += counts[i0 + 1];
    red[t] = s;
    __syncthreads();
    for (int off = SCAN_T / 2; off > 0; off >>= 1) {
        if (t < off) red[t] += red[t + off];
        __syncthreads();
    }
    if (t == 0) tilesums[blockIdx.x] = red[0];
}

__global__ void scan_tops(const int* __restrict__ tilesums, int* __restrict__ tilebase, int ntiles) {
    __shared__ int sh[SCAN_T];
    int t = threadIdx.x;
    int v = (t < ntiles) ? tilesums[t] : 0;
    sh[t] = v;
    __syncthreads();
    for (int off = 1; off < SCAN_T; off <<= 1) {
        int u = (t >= off) ? sh[t - off] : 0;
        __syncthreads();
        sh[t] += u;
        __syncthreads();
    }
    tilebase[t] = sh[t] - v;
}

__global__ void scan_final(const int* __restrict__ counts, const int* __restrict__ tilebase,
                           int* __restrict__ base, int N, int E) {
    __shared__ int sh[SCAN_T];
    int t  = threadIdx.x;
    int i0 = blockIdx.x * SCAN_TILE + 2 * t;
    int a   = (i0     < N) ? counts[i0]     : 0;
    int b   = (i0 + 1 < N) ? counts[i0 + 1] : 0;
    int tot = a + b;
    sh[t] = tot;
    __syncthreads();
    for (int off = 1; off < SCAN_T; off <<= 1) {
        int u = (t >= off) ? sh[t - off] : 0;
        __syncthreads();
        sh[t] += u;
        __syncthreads();
    }
    int excl = sh[t] - tot + tilebase[blockIdx.x];
    if (i0 < N)     base[i0]     = excl;
    if (i0 + 1 < N) base[i0 + 1] = excl + a;
    if (blockIdx.x == 0 && t == 0) base[N] = E;
}

// ---------------- layer 1 aggregate: no-max softmax, fp16 gather, fp16 x1 out ----------------
__global__ void agg1_kernel(const int* __restrict__ edge_src, const int* __restrict__ offsets,
                            const float* __restrict__ as1, const float* __restrict__ ad1,
                            const __half* __restrict__ hx1h, const float* __restrict__ b1,
                            __half* __restrict__ x1h, int N) {
    __shared__ int   ssh[4][64];
    __shared__ float esh[4][64][4];
    int wid  = threadIdx.x >> 6;
    int n    = (blockIdx.x * blockDim.x + threadIdx.x) >> 6;
    int lane = threadIdx.x & 63;
    if (n >= N) return;
    int hsel = lane >> 4;                    // head of cols (2l, 2l+1)
    const float4 ad4 = *(const float4*)(ad1 + 4 * n);
    int beg = offsets[n], end = offsets[n + 1];

    float den[4] = {0.f, 0.f, 0.f, 0.f};
    float acc0 = 0.f, acc1 = 0.f;

    for (int cb = beg; cb < end; cb += 64) {
        int j = cb + lane;
        bool valid = j < end;
        int s = valid ? edge_src[j] : 0;
        float e0 = 0.f, e1 = 0.f, e2 = 0.f, e3 = 0.f;
        if (valid) {
            const float4 a4 = *(const float4*)(as1 + 4 * s);
            float v0 = a4.x + ad4.x, v1 = a4.y + ad4.y;
            float v2 = a4.z + ad4.z, v3 = a4.w + ad4.w;
            v0 = v0 > 0.f ? v0 : 0.2f * v0;
            v1 = v1 > 0.f ? v1 : 0.2f * v1;
            v2 = v2 > 0.f ? v2 : 0.2f * v2;
            v3 = v3 > 0.f ? v3 : 0.2f * v3;
            e0 = __expf(v0); e1 = __expf(v1);
            e2 = __expf(v2); e3 = __expf(v3);
            den[0] += e0; den[1] += e1; den[2] += e2; den[3] += e3;
        }
        ssh[wid][lane] = s;
        *(float4*)&esh[wid][lane][0] = make_float4(e0, e1, e2, e3);

        int cnt = min(64, end - cb);
#pragma unroll 4
        for (int jj = 0; jj < cnt; ++jj) {
            int   sj = ssh[wid][jj];
            float w  = esh[wid][jj][hsel];
            const __half2* hr = (const __half2*)(hx1h + (size_t)sj * C1);
            float2 vf = __half22float2(hr[lane]);
            acc0 += w * vf.x;
            acc1 += w * vf.y;
        }
    }

#pragma unroll
    for (int off = 32; off > 0; off >>= 1)
#pragma unroll
        for (int h = 0; h < 4; ++h) den[h] += __shfl_xor(den[h], off, 64);

    float d = lane < 16 ? den[0] : lane < 32 ? den[1] : lane < 48 ? den[2] : den[3];
    float inv = 1.f / (d + 1e-16f);
    float2 bv = *(const float2*)(b1 + 2 * lane);
    float o0 = acc0 * inv + bv.x;
    float o1 = acc1 * inv + bv.y;
    o0 = o0 > 0.f ? o0 : (__expf(o0) - 1.f);   // ELU
    o1 = o1 > 0.f ? o1 : (__expf(o1) - 1.f);
    *(__half2*)&x1h[(size_t)n * C1 + 2 * lane] = __floats2half2_rn(o0, o1);
}

// ---------------- layer 2 GEMM: hx2 = x1 @ W2 (+ logits); fp16 in, fp16 out ----------------
__global__ __launch_bounds__(256) void gemm2_kernel(
        const __half* __restrict__ x1h, const float* __restrict__ W2,
        const float* __restrict__ attS, const float* __restrict__ attD,
        __half* __restrict__ hx2h, float* __restrict__ as2, float* __restrict__ ad2,
        int N) {
    __shared__ float xT[BK2][64 + 4];
    __shared__ float ws2[BK2][D2N];

    int tid = threadIdx.x;
    int tx  = tid & 15;
    int ty  = tid >> 4;
    int n0  = blockIdx.x * 64;

    float acc[4][4];
#pragma unroll
    for (int r = 0; r < 4; ++r)
#pragma unroll
        for (int c = 0; c < 4; ++c) acc[r][c] = 0.f;

    int lr = tid >> 2;                 // 0..63
    int lk = (tid & 3) * 8;            // 0,8,16,24 (8 halves = 16B)
    int xrow = n0 + lr; if (xrow >= N) xrow = N - 1;
    const __half* xptr = x1h + (size_t)xrow * C1;
    int kw = tid >> 4;
    int cw = tx * 4;

    for (int k0 = 0; k0 < C1; k0 += BK2) {
        f16x8 a = *reinterpret_cast<const f16x8*>(xptr + k0 + lk);
        float4 w0 = *(const float4*)(W2 + (size_t)(k0 + kw     ) * D2N + cw);
        float4 w1 = *(const float4*)(W2 + (size_t)(k0 + kw + 16) * D2N + cw);
        __syncthreads();
#pragma unroll
        for (int j = 0; j < 8; ++j) xT[lk + j][lr] = (float)a[j];
        *(float4*)&ws2[kw     ][cw] = w0;
        *(float4*)&ws2[kw + 16][cw] = w1;
        __syncthreads();
#pragma unroll
        for (int k = 0; k < BK2; ++k) {
            float4 xa = *(const float4*)&xT[k][ty * 4];
            float4 wv = *(const float4*)&ws2[k][tx * 4];
            float xr[4] = {xa.x, xa.y, xa.z, xa.w};
            float wc[4] = {wv.x, wv.y, wv.z, wv.w};
#pragma unroll
            for (int r = 0; r < 4; ++r)
#pragma unroll
                for (int c = 0; c < 4; ++c) acc[r][c] += xr[r] * wc[c];
        }
    }

    const float4 asv = *(const float4*)(attS + tx * 4);
    const float4 adv = *(const float4*)(attD + tx * 4);
#pragma unroll
    for (int r = 0; r < 4; ++r) {
        int n = n0 + ty * 4 + r;
        float ts = acc[r][0] * asv.x + acc[r][1] * asv.y + acc[r][2] * asv.z + acc[r][3] * asv.w;
        float td = acc[r][0] * adv.x + acc[r][1] * adv.y + acc[r][2] * adv.z + acc[r][3] * adv.w;
        ts += __shfl_xor(ts, 1); td += __shfl_xor(td, 1);
        ts += __shfl_xor(ts, 2); td += __shfl_xor(td, 2);
        ts += __shfl_xor(ts, 4); td += __shfl_xor(td, 4);
        ts += __shfl_xor(ts, 8); td += __shfl_xor(td, 8);
        if (n < N) {
            *(__half2*)&hx2h[(size_t)n * D2N + tx * 4]     = __floats2half2_rn(acc[r][0], acc[r][1]);
            *(__half2*)&hx2h[(size_t)n * D2N + tx * 4 + 2] = __floats2half2_rn(acc[r][2], acc[r][3]);
            if (tx == 0) { as2[n] = ts; ad2[n] = td; }
        }
    }
}

// ---------------- layer 2 aggregate: no-max softmax, fp16 gather, last num_new nodes ----------------
__global__ void agg2_kernel(const int* __restrict__ edge_src, const int* __restrict__ offsets,
                            const float* __restrict__ as2, const float* __restrict__ ad2,
                            const __half* __restrict__ hx2h, const float* __restrict__ b2,
                            float* __restrict__ out, int N, int num_new) {
    __shared__ int   ssh[4][64];
    __shared__ float esh[4][64];
    int wid  = threadIdx.x >> 6;
    int w    = (blockIdx.x * blockDim.x + threadIdx.x) >> 6;
    int lane = threadIdx.x & 63;
    if (w >= num_new) return;
    int n = N - num_new + w;
    float adn = ad2[n];
    int beg = offsets[n], end = offsets[n + 1];

    float den = 0.f, acc = 0.f;
    for (int cb = beg; cb < end; cb += 64) {
        int j = cb + lane;
        bool valid = j < end;
        int s = valid ? edge_src[j] : 0;
        float e = 0.f;
        if (valid) {
            float v = as2[s] + adn;
            v = v > 0.f ? v : 0.2f * v;
            e = __expf(v);
            den += e;
        }
        ssh[wid][lane] = s;
        esh[wid][lane] = e;

        int cnt = min(64, end - cb);
#pragma unroll 4
        for (int jj = 0; jj < cnt; ++jj) {
            int   sj = ssh[wid][jj];
            float wj = esh[wid][jj];
            acc += wj * __half2float(hx2h[(size_t)sj * D2N + lane]);
        }
    }
#pragma unroll
    for (int off = 32; off > 0; off >>= 1) den += __shfl_xor(den, off, 64);
    out[(size_t)w * D2N + lane] = acc / (den + 1e-16f) + b2[lane];
}

// ---------------- launch ----------------
extern "C" void kernel_launch(void* const* d_in, const int* in_sizes, int n_in,
                              void* d_out, int out_size, void* d_ws, size_t ws_size,
                              hipStream_t stream) {
    const float* x      = (const float*)d_in[0];
    const int*   src    = (const int*)d_in[1];
    const int*   dst    = (const int*)d_in[2];
    const float* W1     = (const float*)d_in[3];
    const float* attS1  = (const float*)d_in[4];
    const float* attD1  = (const float*)d_in[5];
    const float* b1     = (const float*)d_in[6];
    const float* W2     = (const float*)d_in[7];
    const float* attS2  = (const float*)d_in[8];
    const float* attD2  = (const float*)d_in[9];
    const float* b2     = (const float*)d_in[10];

    const int N = in_sizes[0] / F_IN;   // 50000
    const int E = in_sizes[1];          // 1000000
    const int num_new = out_size / D2N; // 10000
    const int ngemm  = (N + 63) / 64;                     // 782
    const int nbuk   = (N + 255) >> 8;                    // 196
    const int M      = nbuk * NBLK_P;                     // 50176
    const int ntilesM = (M + SCAN_TILE - 1) / SCAN_TILE;  // 98
    const int chunk  = (E + NBLK_P - 1) / NBLK_P;         // 3907

    // workspace carve-up
    __half* hx1h = (__half*)d_ws;                        // N*128 halves
    __half* x1h  = hx1h + (size_t)N * C1;                // N*128 halves
    __half* hx2h = x1h  + (size_t)N * C1;                // N*64 halves
    float* as1 = (float*)(hx2h + (size_t)N * D2N);       // N*4
    float* ad1 = as1 + (size_t)N * H1N;                  // N*4
    float* as2 = ad1 + (size_t)N * H1N;                  // N
    float* ad2 = as2 + N;                                // N
    int* bcounts  = (int*)(ad2 + N);                     // M
    int* bbase    = bcounts + M;                         // M+1
    int* offsets  = bbase + M + 1;                       // N+1
    int* tilesums = offsets + N + 1;                     // 256
    int* tilebase = tilesums + 256;                      // 256
    int* edge_src = tilebase + 256;                      // E
    int2* pedge   = (int2*)(edge_src + E);               // E int2
    __half* W1T   = (__half*)(pedge + E);                // 128*256 halves

    float* out = (float*)d_out;

    hipLaunchKernelGGL(prep_kernel, dim3(C1 + NBLK_P), dim3(256), 0, stream,
                       W1, W1T, dst, bcounts, E, chunk, nbuk);
    hipLaunchKernelGGL(scan_partial, dim3(ntilesM), dim3(SCAN_T), 0, stream, bcounts, tilesums, M);
    hipLaunchKernelGGL(scan_tops, dim3(1), dim3(SCAN_T), 0, stream, tilesums, tilebase, ntilesM);
    hipLaunchKernelGGL(scan_final, dim3(ntilesM), dim3(SCAN_T), 0, stream,
                       bcounts, tilebase, bbase, M, E);
    hipLaunchKernelGGL(gemm1_scatter_kernel, dim3(ngemm + NBLK_P), dim3(256), 0, stream,
                       x, W1T, attS1, attD1, hx1h, as1, ad1, N,
                       src, dst, bbase, pedge, E, chunk, nbuk, ngemm);
    hipLaunchKernelGGL(part_csr, dim3(nbuk), dim3(256), 0, stream,
                       pedge, bbase, offsets, edge_src, N, E, nbuk);
    hipLaunchKernelGGL(agg1_kernel, dim3((N + 3) / 4), dim3(256), 0, stream,
                       edge_src, offsets, as1, ad1, hx1h, b1, x1h, N);
    hipLaunchKernelGGL(gemm2_kernel, dim3((N + 63) / 64), dim3(256), 0, stream,
                       x1h, W2, attS2, attD2, hx2h, as2, ad2, N);
    hipLaunchKernelGGL(agg2_kernel, dim3((num_new + 3) / 4), dim3(256), 0, stream,
                       edge_src, offsets, as2, ad2, hx2h, b2, out, N, num_new);
}

// Round 23
// 143.607 us; speedup vs baseline: 1.0934x; 1.0161x over previous
//
#include <hip/hip_runtime.h>
#include <hip/hip_fp16.h>
#include <math.h>

#define F_IN   256
#define C1     128   // H1*D1
#define H1N    4
#define D2N    64

#define SCAN_T    256
#define SCAN_TILE 512   // 2 elements per thread

#define BK2 32          // gemm2 K-tile

#define NBLK_P 256      // partition blocks
#define NBUK_MAX 256    // max coarse buckets (dst >> 8)

typedef __attribute__((ext_vector_type(8))) _Float16 f16x8;
typedef __attribute__((ext_vector_type(4))) float    f32x4;

// ---------------- prep: W1 transpose (blocks<128) + bucket histogram (rest) ----------------
__global__ void prep_kernel(const float* __restrict__ W1, __half* __restrict__ W1T,
                            const int* __restrict__ dst, int* __restrict__ bcounts,
                            int E, int chunk, int nbuk) {
    if ((int)blockIdx.x < C1) {
        int c = blockIdx.x;
        for (int k = threadIdx.x; k < F_IN; k += blockDim.x)
            W1T[(size_t)c * F_IN + k] = __float2half(W1[(size_t)k * C1 + c]);
        return;
    }
    __shared__ int h[NBUK_MAX];
    int b = blockIdx.x - C1;                  // 0..NBLK_P-1
    for (int t = threadIdx.x; t < nbuk; t += blockDim.x) h[t] = 0;
    __syncthreads();
    int lo = b * chunk, hi = min(lo + chunk, E);
    for (int i = lo + threadIdx.x; i < hi; i += blockDim.x)
        atomicAdd(&h[dst[i] >> 8], 1);                 // LDS atomic
    __syncthreads();
    for (int t = threadIdx.x; t < nbuk; t += blockDim.x)
        bcounts[(size_t)t * NBLK_P + b] = h[t];
}

// ---------------- fused: layer-1 MFMA GEMM BM=32 (blocks < ngemm) + edge partition ----------------
// BM 64->32: grid 782->1563 blocks (~7/CU with scatter) — doubles the number of
// independent latency streams per CU; per-block critical path unchanged.
// Wave wv: rows (wv&1)*16..+15, cols (wv>>1)*64..+63 (heads c0/32, c0/32+1 complete).
__global__ __launch_bounds__(256) void gemm1_scatter_kernel(
        const float* __restrict__ x, const __half* __restrict__ W1T,
        const float* __restrict__ attS, const float* __restrict__ attD,
        __half* __restrict__ hx1h, float* __restrict__ as1, float* __restrict__ ad1,
        int N,
        const int* __restrict__ src, const int* __restrict__ dst,
        const int* __restrict__ bbase, int2* __restrict__ pedge,
        int E, int chunk, int nbuk, int ngemm) {
    if ((int)blockIdx.x >= ngemm) {
        __shared__ int cur[NBUK_MAX];
        int b = blockIdx.x - ngemm;           // 0..NBLK_P-1
        for (int t = threadIdx.x; t < nbuk; t += blockDim.x)
            cur[t] = bbase[(size_t)t * NBLK_P + b];
        __syncthreads();
        int lo = b * chunk, hi = min(lo + chunk, E);
        for (int i = lo + threadIdx.x; i < hi; i += blockDim.x) {
            int d = dst[i];
            int p = atomicAdd(&cur[d >> 8], 1);        // LDS atomic
            pedge[p] = make_int2(src[i], d);
        }
        return;
    }

    __shared__ __half xh[32][40];   // 80B row stride: 16B-aligned, 2-way banks max

    int tid = threadIdx.x;
    int wv  = tid >> 6;             // wave 0..3
    int l   = tid & 63;
    int n0  = blockIdx.x * 32;

    f32x4 acc[4];
#pragma unroll
    for (int t = 0; t < 4; ++t) acc[t] = (f32x4){0.f, 0.f, 0.f, 0.f};

    int srow = tid >> 3;                  // 0..31
    int skg  = (tid & 7) * 4;             // 0,4,...,28
    int xrow = n0 + srow; if (xrow >= N) xrow = N - 1;   // clamp (stores guarded)
    const float* xptr = x + (size_t)xrow * F_IN;

    int r0 = (wv & 1) * 16;               // wave's row tile
    int c0 = (wv >> 1) * 64;              // wave's col half
    int arow = r0 + (l & 15);             // A row within block tile
    int akk  = (l >> 4) * 8;              // A k-run
    int bcol = l & 15;                    // B col within 16-col tile
    int bkk  = (l >> 4) * 8;              // B k-run

    // prologue: load K-step 0 (one float4/thread covers 32x32 tile)
    float4 a0 = *(const float4*)(xptr + skg);

    for (int s = 0; s < 8; ++s) {
        int k0 = s * 32;
        __syncthreads();                  // previous tile consumed
        __half2* dp = (__half2*)&xh[srow][skg];
        dp[0] = __floats2half2_rn(a0.x, a0.y);
        dp[1] = __floats2half2_rn(a0.z, a0.w);
        __syncthreads();
        if (s < 7)                        // prefetch next K-step
            a0 = *(const float4*)(xptr + k0 + 32 + skg);
        f16x8 af = *reinterpret_cast<const f16x8*>(&xh[arow][akk]);
#pragma unroll
        for (int t = 0; t < 4; ++t) {
            f16x8 bf = *reinterpret_cast<const f16x8*>(
                W1T + (size_t)(c0 + 16 * t + bcol) * F_IN + k0 + bkk);
            acc[t] = __builtin_amdgcn_mfma_f32_16x16x32_f16(af, bf, acc[t], 0, 0, 0);
        }
    }

    // epilogue: D layout col = l&15, row = 4*(l>>4)+r
    float aS[4], aD[4];
#pragma unroll
    for (int t = 0; t < 4; ++t) {
        aS[t] = attS[c0 + 16 * t + bcol];
        aD[t] = attD[c0 + 16 * t + bcol];
    }
    int hA = c0 >> 5;                     // first head owned by this wave (0 or 2)
#pragma unroll
    for (int r = 0; r < 4; ++r) {
        int n = n0 + r0 + 4 * (l >> 4) + r;
        float ts0 = acc[0][r] * aS[0] + acc[1][r] * aS[1];
        float td0 = acc[0][r] * aD[0] + acc[1][r] * aD[1];
        float ts1 = acc[2][r] * aS[2] + acc[3][r] * aS[3];
        float td1 = acc[2][r] * aD[2] + acc[3][r] * aD[3];
#pragma unroll
        for (int off = 1; off <= 8; off <<= 1) {
            ts0 += __shfl_xor(ts0, off, 64); td0 += __shfl_xor(td0, off, 64);
            ts1 += __shfl_xor(ts1, off, 64); td1 += __shfl_xor(td1, off, 64);
        }
        if (n < N) {
#pragma unroll
            for (int t = 0; t < 4; ++t)
                hx1h[(size_t)n * C1 + c0 + 16 * t + bcol] = __float2half(acc[t][r]);
            if (bcol == 0) {
                as1[n * H1N + hA]     = ts0; ad1[n * H1N + hA]     = td0;
                as1[n * H1N + hA + 1] = ts1; ad1[n * H1N + hA + 1] = td1;
            }
        }
    }
}

// ---------------- CSR build pass D: per-bucket fine CSR (256 nodes/bucket) ----------------
__global__ __launch_bounds__(256) void part_csr(
        const int2* __restrict__ pedge, const int* __restrict__ bbase,
        int* __restrict__ offsets, int* __restrict__ edge_src,
        int N, int E, int nbuk) {
    __shared__ int fcnt[256];
    __shared__ int fsc[256];
    int b = blockIdx.x;
    int t = threadIdx.x;
    int ebeg = bbase[(size_t)b * NBLK_P];
    int eend = (b + 1 < nbuk) ? bbase[(size_t)(b + 1) * NBLK_P] : E;
    int nbase = b << 8;
    fcnt[t] = 0;
    __syncthreads();
    for (int i = ebeg + t; i < eend; i += 256)
        atomicAdd(&fcnt[pedge[i].y - nbase], 1);       // LDS atomic
    __syncthreads();
    int v = fcnt[t];
    fsc[t] = v;
    __syncthreads();
    for (int off = 1; off < 256; off <<= 1) {
        int u = (t >= off) ? fsc[t - off] : 0;
        __syncthreads();
        fsc[t] += u;
        __syncthreads();
    }
    int goff = ebeg + fsc[t] - v;                      // global CSR start of node nbase+t
    int node = nbase + t;
    if (node < N) offsets[node] = goff;
    if (b == nbuk - 1 && t == 0) offsets[N] = E;
    __syncthreads();
    fcnt[t] = goff;                                    // reuse as cursor
    __syncthreads();
    for (int i = ebeg + t; i < eend; i += 256) {
        int2 e = pedge[i];
        int p = atomicAdd(&fcnt[e.y - nbase], 1);      // LDS atomic
        edge_src[p] = e.x;
    }
}

// ---------------- scan: generic hierarchical exclusive scan ----------------
__global__ void scan_partial(const int* __restrict__ counts, int* __restrict__ tilesums, int N) {
    __shared__ int red[SCAN_T];
    int t  = threadIdx.x;
    int i0 = blockIdx.x * SCAN_TILE + 2 * t;
    int s = 0;
    if (i0     < N) s += counts[i0];
    if (i0 + 1 < N) s += counts[i0 + 1];
    red[t] = s;
    __syncthreads();
    for (int off = SCAN_T / 2; off > 0; off >>= 1) {
        if (t < off) red[t] += red[t + off];
        __syncthreads();
    }
    if (t == 0) tilesums[blockIdx.x] = red[0];
}

__global__ void scan_tops(const int* __restrict__ tilesums, int* __restrict__ tilebase, int ntiles) {
    __shared__ int sh[SCAN_T];
    int t = threadIdx.x;
    int v = (t < ntiles) ? tilesums[t] : 0;
    sh[t] = v;
    __syncthreads();
    for (int off = 1; off < SCAN_T; off <<= 1) {
        int u = (t >= off) ? sh[t - off] : 0;
        __syncthreads();
        sh[t] += u;
        __syncthreads();
    }
    tilebase[t] = sh[t] - v;
}

__global__ void scan_final(const int* __restrict__ counts, const int* __restrict__ tilebase,
                           int* __restrict__ base, int N, int E) {
    __shared__ int sh[SCAN_T];
    int t  = threadIdx.x;
    int i0 = blockIdx.x * SCAN_TILE + 2 * t;
    int a   = (i0     < N) ? counts[i0]     : 0;
    int b   = (i0 + 1 < N) ? counts[i0 + 1] : 0;
    int tot = a + b;
    sh[t] = tot;
    __syncthreads();
    for (int off = 1; off < SCAN_T; off <<= 1) {
        int u = (t >= off) ? sh[t - off] : 0;
        __syncthreads();
        sh[t] += u;
        __syncthreads();
    }
    int excl = sh[t] - tot + tilebase[blockIdx.x];
    if (i0 < N)     base[i0]     = excl;
    if (i0 + 1 < N) base[i0 + 1] = excl + a;
    if (blockIdx.x == 0 && t == 0) base[N] = E;
}

// ---------------- layer 1 aggregate: no-max softmax, fp16 gather, fp16 x1 out ----------------
__global__ void agg1_kernel(const int* __restrict__ edge_src, const int* __restrict__ offsets,
                            const float* __restrict__ as1, const float* __restrict__ ad1,
                            const __half* __restrict__ hx1h, const float* __restrict__ b1,
                            __half* __restrict__ x1h, int N) {
    __shared__ int   ssh[4][64];
    __shared__ float esh[4][64][4];
    int wid  = threadIdx.x >> 6;
    int n    = (blockIdx.x * blockDim.x + threadIdx.x) >> 6;
    int lane = threadIdx.x & 63;
    if (n >= N) return;
    int hsel = lane >> 4;                    // head of cols (2l, 2l+1)
    const float4 ad4 = *(const float4*)(ad1 + 4 * n);
    int beg = offsets[n], end = offsets[n + 1];

    float den[4] = {0.f, 0.f, 0.f, 0.f};
    float acc0 = 0.f, acc1 = 0.f;

    for (int cb = beg; cb < end; cb += 64) {
        int j = cb + lane;
        bool valid = j < end;
        int s = valid ? edge_src[j] : 0;
        float e0 = 0.f, e1 = 0.f, e2 = 0.f, e3 = 0.f;
        if (valid) {
            const float4 a4 = *(const float4*)(as1 + 4 * s);
            float v0 = a4.x + ad4.x, v1 = a4.y + ad4.y;
            float v2 = a4.z + ad4.z, v3 = a4.w + ad4.w;
            v0 = v0 > 0.f ? v0 : 0.2f * v0;
            v1 = v1 > 0.f ? v1 : 0.2f * v1;
            v2 = v2 > 0.f ? v2 : 0.2f * v2;
            v3 = v3 > 0.f ? v3 : 0.2f * v3;
            e0 = __expf(v0); e1 = __expf(v1);
            e2 = __expf(v2); e3 = __expf(v3);
            den[0] += e0; den[1] += e1; den[2] += e2; den[3] += e3;
        }
        ssh[wid][lane] = s;
        *(float4*)&esh[wid][lane][0] = make_float4(e0, e1, e2, e3);

        int cnt = min(64, end - cb);
#pragma unroll 4
        for (int jj = 0; jj < cnt; ++jj) {
            int   sj = ssh[wid][jj];
            float w  = esh[wid][jj][hsel];
            const __half2* hr = (const __half2*)(hx1h + (size_t)sj * C1);
            float2 vf = __half22float2(hr[lane]);
            acc0 += w * vf.x;
            acc1 += w * vf.y;
        }
    }

#pragma unroll
    for (int off = 32; off > 0; off >>= 1)
#pragma unroll
        for (int h = 0; h < 4; ++h) den[h] += __shfl_xor(den[h], off, 64);

    float d = lane < 16 ? den[0] : lane < 32 ? den[1] : lane < 48 ? den[2] : den[3];
    float inv = 1.f / (d + 1e-16f);
    float2 bv = *(const float2*)(b1 + 2 * lane);
    float o0 = acc0 * inv + bv.x;
    float o1 = acc1 * inv + bv.y;
    o0 = o0 > 0.f ? o0 : (__expf(o0) - 1.f);   // ELU
    o1 = o1 > 0.f ? o1 : (__expf(o1) - 1.f);
    *(__half2*)&x1h[(size_t)n * C1 + 2 * lane] = __floats2half2_rn(o0, o1);
}

// ---------------- layer 2 GEMM: hx2 = x1 @ W2 (+ logits); fp16 in, fp16 out ----------------
__global__ __launch_bounds__(256) void gemm2_kernel(
        const __half* __restrict__ x1h, const float* __restrict__ W2,
        const float* __restrict__ attS, const float* __restrict__ attD,
        __half* __restrict__ hx2h, float* __restrict__ as2, float* __restrict__ ad2,
        int N) {
    __shared__ float xT[BK2][64 + 4];
    __shared__ float ws2[BK2][D2N];

    int tid = threadIdx.x;
    int tx  = tid & 15;
    int ty  = tid >> 4;
    int n0  = blockIdx.x * 64;

    float acc[4][4];
#pragma unroll
    for (int r = 0; r < 4; ++r)
#pragma unroll
        for (int c = 0; c < 4; ++c) acc[r][c] = 0.f;

    int lr = tid >> 2;                 // 0..63
    int lk = (tid & 3) * 8;            // 0,8,16,24 (8 halves = 16B)
    int xrow = n0 + lr; if (xrow >= N) xrow = N - 1;
    const __half* xptr = x1h + (size_t)xrow * C1;
    int kw = tid >> 4;
    int cw = tx * 4;

    for (int k0 = 0; k0 < C1; k0 += BK2) {
        f16x8 a = *reinterpret_cast<const f16x8*>(xptr + k0 + lk);
        float4 w0 = *(const float4*)(W2 + (size_t)(k0 + kw     ) * D2N + cw);
        float4 w1 = *(const float4*)(W2 + (size_t)(k0 + kw + 16) * D2N + cw);
        __syncthreads();
#pragma unroll
        for (int j = 0; j < 8; ++j) xT[lk + j][lr] = (float)a[j];
        *(float4*)&ws2[kw     ][cw] = w0;
        *(float4*)&ws2[kw + 16][cw] = w1;
        __syncthreads();
#pragma unroll
        for (int k = 0; k < BK2; ++k) {
            float4 xa = *(const float4*)&xT[k][ty * 4];
            float4 wv = *(const float4*)&ws2[k][tx * 4];
            float xr[4] = {xa.x, xa.y, xa.z, xa.w};
            float wc[4] = {wv.x, wv.y, wv.z, wv.w};
#pragma unroll
            for (int r = 0; r < 4; ++r)
#pragma unroll
                for (int c = 0; c < 4; ++c) acc[r][c] += xr[r] * wc[c];
        }
    }

    const float4 asv = *(const float4*)(attS + tx * 4);
    const float4 adv = *(const float4*)(attD + tx * 4);
#pragma unroll
    for (int r = 0; r < 4; ++r) {
        int n = n0 + ty * 4 + r;
        float ts = acc[r][0] * asv.x + acc[r][1] * asv.y + acc[r][2] * asv.z + acc[r][3] * asv.w;
        float td = acc[r][0] * adv.x + acc[r][1] * adv.y + acc[r][2] * adv.z + acc[r][3] * adv.w;
        ts += __shfl_xor(ts, 1); td += __shfl_xor(td, 1);
        ts += __shfl_xor(ts, 2); td += __shfl_xor(td, 2);
        ts += __shfl_xor(ts, 4); td += __shfl_xor(td, 4);
        ts += __shfl_xor(ts, 8); td += __shfl_xor(td, 8);
        if (n < N) {
            *(__half2*)&hx2h[(size_t)n * D2N + tx * 4]     = __floats2half2_rn(acc[r][0], acc[r][1]);
            *(__half2*)&hx2h[(size_t)n * D2N + tx * 4 + 2] = __floats2half2_rn(acc[r][2], acc[r][3]);
            if (tx == 0) { as2[n] = ts; ad2[n] = td; }
        }
    }
}

// ---------------- layer 2 aggregate: no-max softmax, fp16 gather, last num_new nodes ----------------
__global__ void agg2_kernel(const int* __restrict__ edge_src, const int* __restrict__ offsets,
                            const float* __restrict__ as2, const float* __restrict__ ad2,
                            const __half* __restrict__ hx2h, const float* __restrict__ b2,
                            float* __restrict__ out, int N, int num_new) {
    __shared__ int   ssh[4][64];
    __shared__ float esh[4][64];
    int wid  = threadIdx.x >> 6;
    int w    = (blockIdx.x * blockDim.x + threadIdx.x) >> 6;
    int lane = threadIdx.x & 63;
    if (w >= num_new) return;
    int n = N - num_new + w;
    float adn = ad2[n];
    int beg = offsets[n], end = offsets[n + 1];

    float den = 0.f, acc = 0.f;
    for (int cb = beg; cb < end; cb += 64) {
        int j = cb + lane;
        bool valid = j < end;
        int s = valid ? edge_src[j] : 0;
        float e = 0.f;
        if (valid) {
            float v = as2[s] + adn;
            v = v > 0.f ? v : 0.2f * v;
            e = __expf(v);
            den += e;
        }
        ssh[wid][lane] = s;
        esh[wid][lane] = e;

        int cnt = min(64, end - cb);
#pragma unroll 4
        for (int jj = 0; jj < cnt; ++jj) {
            int   sj = ssh[wid][jj];
            float wj = esh[wid][jj];
            acc += wj * __half2float(hx2h[(size_t)sj * D2N + lane]);
        }
    }
#pragma unroll
    for (int off = 32; off > 0; off >>= 1) den += __shfl_xor(den, off, 64);
    out[(size_t)w * D2N + lane] = acc / (den + 1e-16f) + b2[lane];
}

// ---------------- launch ----------------
extern "C" void kernel_launch(void* const* d_in, const int* in_sizes, int n_in,
                              void* d_out, int out_size, void* d_ws, size_t ws_size,
                              hipStream_t stream) {
    const float* x      = (const float*)d_in[0];
    const int*   src    = (const int*)d_in[1];
    const int*   dst    = (const int*)d_in[2];
    const float* W1     = (const float*)d_in[3];
    const float* attS1  = (const float*)d_in[4];
    const float* attD1  = (const float*)d_in[5];
    const float* b1     = (const float*)d_in[6];
    const float* W2     = (const float*)d_in[7];
    const float* attS2  = (const float*)d_in[8];
    const float* attD2  = (const float*)d_in[9];
    const float* b2     = (const float*)d_in[10];

    const int N = in_sizes[0] / F_IN;   // 50000
    const int E = in_sizes[1];          // 1000000
    const int num_new = out_size / D2N; // 10000
    const int ngemm  = (N + 31) / 32;                     // 1563
    const int nbuk   = (N + 255) >> 8;                    // 196
    const int M      = nbuk * NBLK_P;                     // 50176
    const int ntilesM = (M + SCAN_TILE - 1) / SCAN_TILE;  // 98
    const int chunk  = (E + NBLK_P - 1) / NBLK_P;         // 3907

    // workspace carve-up
    __half* hx1h = (__half*)d_ws;                        // N*128 halves
    __half* x1h  = hx1h + (size_t)N * C1;                // N*128 halves
    __half* hx2h = x1h  + (size_t)N * C1;                // N*64 halves
    float* as1 = (float*)(hx2h + (size_t)N * D2N);       // N*4
    float* ad1 = as1 + (size_t)N * H1N;                  // N*4
    float* as2 = ad1 + (size_t)N * H1N;                  // N
    float* ad2 = as2 + N;                                // N
    int* bcounts  = (int*)(ad2 + N);                     // M
    int* bbase    = bcounts + M;                         // M+1
    int* offsets  = bbase + M + 1;                       // N+1
    int* tilesums = offsets + N + 1;                     // 256
    int* tilebase = tilesums + 256;                      // 256
    int* edge_src = tilebase + 256;                      // E
    int2* pedge   = (int2*)(edge_src + E);               // E int2
    __half* W1T   = (__half*)(pedge + E);                // 128*256 halves

    float* out = (float*)d_out;

    hipLaunchKernelGGL(prep_kernel, dim3(C1 + NBLK_P), dim3(256), 0, stream,
                       W1, W1T, dst, bcounts, E, chunk, nbuk);
    hipLaunchKernelGGL(scan_partial, dim3(ntilesM), dim3(SCAN_T), 0, stream, bcounts, tilesums, M);
    hipLaunchKernelGGL(scan_tops, dim3(1), dim3(SCAN_T), 0, stream, tilesums, tilebase, ntilesM);
    hipLaunchKernelGGL(scan_final, dim3(ntilesM), dim3(SCAN_T), 0, stream,
                       bcounts, tilebase, bbase, M, E);
    hipLaunchKernelGGL(gemm1_scatter_kernel, dim3(ngemm + NBLK_P), dim3(256), 0, stream,
                       x, W1T, attS1, attD1, hx1h, as1, ad1, N,
                       src, dst, bbase, pedge, E, chunk, nbuk, ngemm);
    hipLaunchKernelGGL(part_csr, dim3(nbuk), dim3(256), 0, stream,
                       pedge, bbase, offsets, edge_src, N, E, nbuk);
    hipLaunchKernelGGL(agg1_kernel, dim3((N + 3) / 4), dim3(256), 0, stream,
                       edge_src, offsets, as1, ad1, hx1h, b1, x1h, N);
    hipLaunchKernelGGL(gemm2_kernel, dim3((N + 63) / 64), dim3(256), 0, stream,
                       x1h, W2, attS2, attD2, hx2h, as2, ad2, N);
    hipLaunchKernelGGL(agg2_kernel, dim3((num_new + 3) / 4), dim3(256), 0, stream,
                       edge_src, offsets, as2, ad2, hx2h, b2, out, N, num_new);
}

// Round 24
// 139.396 us; speedup vs baseline: 1.1264x; 1.0302x over previous
//
#include <hip/hip_runtime.h>
#include <hip/hip_fp16.h>
#include <math.h>

#define F_IN   256
#define C1     128   // H1*D1
#define H1N    4
#define D2N    64

#define SCAN_T    256
#define SCAN_TILE 512   // 2 elements per thread

#define BK2 32          // gemm2 K-tile

#define NBLK_P 256      // partition blocks
#define NBUK_MAX 256    // max coarse buckets (dst >> 8)

typedef __attribute__((ext_vector_type(8))) _Float16 f16x8;
typedef __attribute__((ext_vector_type(4))) float    f32x4;

// ---------------- prep: W1 transpose (blocks<128) + bucket histogram (rest) ----------------
__global__ void prep_kernel(const float* __restrict__ W1, __half* __restrict__ W1T,
                            const int* __restrict__ dst, int* __restrict__ bcounts,
                            int E, int chunk, int nbuk) {
    if ((int)blockIdx.x < C1) {
        int c = blockIdx.x;
        for (int k = threadIdx.x; k < F_IN; k += blockDim.x)
            W1T[(size_t)c * F_IN + k] = __float2half(W1[(size_t)k * C1 + c]);
        return;
    }
    __shared__ int h[NBUK_MAX];
    int b = blockIdx.x - C1;                  // 0..NBLK_P-1
    for (int t = threadIdx.x; t < nbuk; t += blockDim.x) h[t] = 0;
    __syncthreads();
    int lo = b * chunk, hi = min(lo + chunk, E);
    for (int i = lo + threadIdx.x; i < hi; i += blockDim.x)
        atomicAdd(&h[dst[i] >> 8], 1);                 // LDS atomic
    __syncthreads();
    for (int t = threadIdx.x; t < nbuk; t += blockDim.x)
        bcounts[(size_t)t * NBLK_P + b] = h[t];
}

// ---------------- fused: layer-1 MFMA GEMM BM=32 (blocks < ngemm) + edge partition ----------------
__global__ __launch_bounds__(256) void gemm1_scatter_kernel(
        const float* __restrict__ x, const __half* __restrict__ W1T,
        const float* __restrict__ attS, const float* __restrict__ attD,
        __half* __restrict__ hx1h, float* __restrict__ as1, float* __restrict__ ad1,
        int N,
        const int* __restrict__ src, const int* __restrict__ dst,
        const int* __restrict__ bbase, int2* __restrict__ pedge,
        int E, int chunk, int nbuk, int ngemm) {
    if ((int)blockIdx.x >= ngemm) {
        __shared__ int cur[NBUK_MAX];
        int b = blockIdx.x - ngemm;           // 0..NBLK_P-1
        for (int t = threadIdx.x; t < nbuk; t += blockDim.x)
            cur[t] = bbase[(size_t)t * NBLK_P + b];
        __syncthreads();
        int lo = b * chunk, hi = min(lo + chunk, E);
        for (int i = lo + threadIdx.x; i < hi; i += blockDim.x) {
            int d = dst[i];
            int p = atomicAdd(&cur[d >> 8], 1);        // LDS atomic
            pedge[p] = make_int2(src[i], d);
        }
        return;
    }

    __shared__ __half xh[32][40];   // 80B row stride: 16B-aligned, 2-way banks max

    int tid = threadIdx.x;
    int wv  = tid >> 6;             // wave 0..3
    int l   = tid & 63;
    int n0  = blockIdx.x * 32;

    f32x4 acc[4];
#pragma unroll
    for (int t = 0; t < 4; ++t) acc[t] = (f32x4){0.f, 0.f, 0.f, 0.f};

    int srow = tid >> 3;                  // 0..31
    int skg  = (tid & 7) * 4;             // 0,4,...,28
    int xrow = n0 + srow; if (xrow >= N) xrow = N - 1;   // clamp (stores guarded)
    const float* xptr = x + (size_t)xrow * F_IN;

    int r0 = (wv & 1) * 16;               // wave's row tile
    int c0 = (wv >> 1) * 64;              // wave's col half
    int arow = r0 + (l & 15);             // A row within block tile
    int akk  = (l >> 4) * 8;              // A k-run
    int bcol = l & 15;                    // B col within 16-col tile
    int bkk  = (l >> 4) * 8;              // B k-run

    float4 a0 = *(const float4*)(xptr + skg);   // prologue: K-step 0

    for (int s = 0; s < 8; ++s) {
        int k0 = s * 32;
        __syncthreads();                  // previous tile consumed
        __half2* dp = (__half2*)&xh[srow][skg];
        dp[0] = __floats2half2_rn(a0.x, a0.y);
        dp[1] = __floats2half2_rn(a0.z, a0.w);
        __syncthreads();
        if (s < 7)                        // prefetch next K-step
            a0 = *(const float4*)(xptr + k0 + 32 + skg);
        f16x8 af = *reinterpret_cast<const f16x8*>(&xh[arow][akk]);
#pragma unroll
        for (int t = 0; t < 4; ++t) {
            f16x8 bf = *reinterpret_cast<const f16x8*>(
                W1T + (size_t)(c0 + 16 * t + bcol) * F_IN + k0 + bkk);
            acc[t] = __builtin_amdgcn_mfma_f32_16x16x32_f16(af, bf, acc[t], 0, 0, 0);
        }
    }

    // epilogue: D layout col = l&15, row = 4*(l>>4)+r
    float aS[4], aD[4];
#pragma unroll
    for (int t = 0; t < 4; ++t) {
        aS[t] = attS[c0 + 16 * t + bcol];
        aD[t] = attD[c0 + 16 * t + bcol];
    }
    int hA = c0 >> 5;                     // first head owned by this wave (0 or 2)
#pragma unroll
    for (int r = 0; r < 4; ++r) {
        int n = n0 + r0 + 4 * (l >> 4) + r;
        float ts0 = acc[0][r] * aS[0] + acc[1][r] * aS[1];
        float td0 = acc[0][r] * aD[0] + acc[1][r] * aD[1];
        float ts1 = acc[2][r] * aS[2] + acc[3][r] * aS[3];
        float td1 = acc[2][r] * aD[2] + acc[3][r] * aD[3];
#pragma unroll
        for (int off = 1; off <= 8; off <<= 1) {
            ts0 += __shfl_xor(ts0, off, 64); td0 += __shfl_xor(td0, off, 64);
            ts1 += __shfl_xor(ts1, off, 64); td1 += __shfl_xor(td1, off, 64);
        }
        if (n < N) {
#pragma unroll
            for (int t = 0; t < 4; ++t)
                hx1h[(size_t)n * C1 + c0 + 16 * t + bcol] = __float2half(acc[t][r]);
            if (bcol == 0) {
                as1[n * H1N + hA]     = ts0; ad1[n * H1N + hA]     = td0;
                as1[n * H1N + hA + 1] = ts1; ad1[n * H1N + hA + 1] = td1;
            }
        }
    }
}

// ---------------- CSR build pass D: per-bucket fine CSR, 1024 threads/block ----------------
// 196 blocks was 0.77/CU with 256 thr; 1024 thr gives 4x lanes on the two edge loops.
// 256-wide LDS scan phases keep ALL threads at the barriers (tid<256 guards).
__global__ __launch_bounds__(1024) void part_csr(
        const int2* __restrict__ pedge, const int* __restrict__ bbase,
        int* __restrict__ offsets, int* __restrict__ edge_src,
        int N, int E, int nbuk) {
    __shared__ int fcnt[256];
    __shared__ int fsc[256];
    int b   = blockIdx.x;
    int tid = threadIdx.x;
    int ebeg = bbase[(size_t)b * NBLK_P];
    int eend = (b + 1 < nbuk) ? bbase[(size_t)(b + 1) * NBLK_P] : E;
    int nbase = b << 8;
    if (tid < 256) fcnt[tid] = 0;
    __syncthreads();
    for (int i = ebeg + tid; i < eend; i += 1024)
        atomicAdd(&fcnt[pedge[i].y - nbase], 1);       // LDS atomic
    __syncthreads();
    int v = 0;
    if (tid < 256) { v = fcnt[tid]; fsc[tid] = v; }
    __syncthreads();
    for (int off = 1; off < 256; off <<= 1) {
        int u = 0;
        if (tid < 256 && tid >= off) u = fsc[tid - off];
        __syncthreads();
        if (tid < 256 && tid >= off) fsc[tid] += u;
        __syncthreads();
    }
    if (tid < 256) {
        int goff = ebeg + fsc[tid] - v;                // global CSR start of node nbase+tid
        int node = nbase + tid;
        if (node < N) offsets[node] = goff;
        fcnt[tid] = goff;                              // reuse as cursor
    }
    if (b == nbuk - 1 && tid == 0) offsets[N] = E;
    __syncthreads();
    for (int i = ebeg + tid; i < eend; i += 1024) {
        int2 e = pedge[i];
        int p = atomicAdd(&fcnt[e.y - nbase], 1);      // LDS atomic
        edge_src[p] = e.x;
    }
}

// ---------------- scan: generic hierarchical exclusive scan ----------------
__global__ void scan_partial(const int* __restrict__ counts, int* __restrict__ tilesums, int N) {
    __shared__ int red[SCAN_T];
    int t  = threadIdx.x;
    int i0 = blockIdx.x * SCAN_TILE + 2 * t;
    int s = 0;
    if (i0     < N) s += counts[i0];
    if (i0 + 1 < N) s += counts[i0 + 1];
    red[t] = s;
    __syncthreads();
    for (int off = SCAN_T / 2; off > 0; off >>= 1) {
        if (t < off) red[t] += red[t + off];
        __syncthreads();
    }
    if (t == 0) tilesums[blockIdx.x] = red[0];
}

__global__ void scan_tops(const int* __restrict__ tilesums, int* __restrict__ tilebase, int ntiles) {
    __shared__ int sh[SCAN_T];
    int t = threadIdx.x;
    int v = (t < ntiles) ? tilesums[t] : 0;
    sh[t] = v;
    __syncthreads();
    for (int off = 1; off < SCAN_T; off <<= 1) {
        int u = (t >= off) ? sh[t - off] : 0;
        __syncthreads();
        sh[t] += u;
        __syncthreads();
    }
    tilebase[t] = sh[t] - v;
}

__global__ void scan_final(const int* __restrict__ counts, const int* __restrict__ tilebase,
                           int* __restrict__ base, int N, int E) {
    __shared__ int sh[SCAN_T];
    int t  = threadIdx.x;
    int i0 = blockIdx.x * SCAN_TILE + 2 * t;
    int a   = (i0     < N) ? counts[i0]     : 0;
    int b   = (i0 + 1 < N) ? counts[i0 + 1] : 0;
    int tot = a + b;
    sh[t] = tot;
    __syncthreads();
    for (int off = 1; off < SCAN_T; off <<= 1) {
        int u = (t >= off) ? sh[t - off] : 0;
        __syncthreads();
        sh[t] += u;
        __syncthreads();
    }
    int excl = sh[t] - tot + tilebase[blockIdx.x];
    if (i0 < N)     base[i0]     = excl;
    if (i0 + 1 < N) base[i0 + 1] = excl + a;
    if (blockIdx.x == 0 && t == 0) base[N] = E;
}

// ---------------- layer 1 aggregate: no-max softmax, fp16 gather, fp16 x1 out ----------------
__global__ void agg1_kernel(const int* __restrict__ edge_src, const int* __restrict__ offsets,
                            const float* __restrict__ as1, const float* __restrict__ ad1,
                            const __half* __restrict__ hx1h, const float* __restrict__ b1,
                            __half* __restrict__ x1h, int N) {
    __shared__ int   ssh[4][64];
    __shared__ float esh[4][64][4];
    int wid  = threadIdx.x >> 6;
    int n    = (blockIdx.x * blockDim.x + threadIdx.x) >> 6;
    int lane = threadIdx.x & 63;
    if (n >= N) return;
    int hsel = lane >> 4;                    // head of cols (2l, 2l+1)
    const float4 ad4 = *(const float4*)(ad1 + 4 * n);
    int beg = offsets[n], end = offsets[n + 1];

    float den[4] = {0.f, 0.f, 0.f, 0.f};
    float acc0 = 0.f, acc1 = 0.f;

    for (int cb = beg; cb < end; cb += 64) {
        int j = cb + lane;
        bool valid = j < end;
        int s = valid ? edge_src[j] : 0;
        float e0 = 0.f, e1 = 0.f, e2 = 0.f, e3 = 0.f;
        if (valid) {
            const float4 a4 = *(const float4*)(as1 + 4 * s);
            float v0 = a4.x + ad4.x, v1 = a4.y + ad4.y;
            float v2 = a4.z + ad4.z, v3 = a4.w + ad4.w;
            v0 = v0 > 0.f ? v0 : 0.2f * v0;
            v1 = v1 > 0.f ? v1 : 0.2f * v1;
            v2 = v2 > 0.f ? v2 : 0.2f * v2;
            v3 = v3 > 0.f ? v3 : 0.2f * v3;
            e0 = __expf(v0); e1 = __expf(v1);
            e2 = __expf(v2); e3 = __expf(v3);
            den[0] += e0; den[1] += e1; den[2] += e2; den[3] += e3;
        }
        ssh[wid][lane] = s;
        *(float4*)&esh[wid][lane][0] = make_float4(e0, e1, e2, e3);

        int cnt = min(64, end - cb);
#pragma unroll 4
        for (int jj = 0; jj < cnt; ++jj) {
            int   sj = ssh[wid][jj];
            float w  = esh[wid][jj][hsel];
            const __half2* hr = (const __half2*)(hx1h + (size_t)sj * C1);
            float2 vf = __half22float2(hr[lane]);
            acc0 += w * vf.x;
            acc1 += w * vf.y;
        }
    }

#pragma unroll
    for (int off = 32; off > 0; off >>= 1)
#pragma unroll
        for (int h = 0; h < 4; ++h) den[h] += __shfl_xor(den[h], off, 64);

    float d = lane < 16 ? den[0] : lane < 32 ? den[1] : lane < 48 ? den[2] : den[3];
    float inv = 1.f / (d + 1e-16f);
    float2 bv = *(const float2*)(b1 + 2 * lane);
    float o0 = acc0 * inv + bv.x;
    float o1 = acc1 * inv + bv.y;
    o0 = o0 > 0.f ? o0 : (__expf(o0) - 1.f);   // ELU
    o1 = o1 > 0.f ? o1 : (__expf(o1) - 1.f);
    *(__half2*)&x1h[(size_t)n * C1 + 2 * lane] = __floats2half2_rn(o0, o1);
}

// ---------------- layer 2 GEMM: hx2 = x1 @ W2 (+ logits); fp16 in, fp16 out ----------------
__global__ __launch_bounds__(256) void gemm2_kernel(
        const __half* __restrict__ x1h, const float* __restrict__ W2,
        const float* __restrict__ attS, const float* __restrict__ attD,
        __half* __restrict__ hx2h, float* __restrict__ as2, float* __restrict__ ad2,
        int N) {
    __shared__ float xT[BK2][64 + 4];
    __shared__ float ws2[BK2][D2N];

    int tid = threadIdx.x;
    int tx  = tid & 15;
    int ty  = tid >> 4;
    int n0  = blockIdx.x * 64;

    float acc[4][4];
#pragma unroll
    for (int r = 0; r < 4; ++r)
#pragma unroll
        for (int c = 0; c < 4; ++c) acc[r][c] = 0.f;

    int lr = tid >> 2;                 // 0..63
    int lk = (tid & 3) * 8;            // 0,8,16,24 (8 halves = 16B)
    int xrow = n0 + lr; if (xrow >= N) xrow = N - 1;
    const __half* xptr = x1h + (size_t)xrow * C1;
    int kw = tid >> 4;
    int cw = tx * 4;

    for (int k0 = 0; k0 < C1; k0 += BK2) {
        f16x8 a = *reinterpret_cast<const f16x8*>(xptr + k0 + lk);
        float4 w0 = *(const float4*)(W2 + (size_t)(k0 + kw     ) * D2N + cw);
        float4 w1 = *(const float4*)(W2 + (size_t)(k0 + kw + 16) * D2N + cw);
        __syncthreads();
#pragma unroll
        for (int j = 0; j < 8; ++j) xT[lk + j][lr] = (float)a[j];
        *(float4*)&ws2[kw     ][cw] = w0;
        *(float4*)&ws2[kw + 16][cw] = w1;
        __syncthreads();
#pragma unroll
        for (int k = 0; k < BK2; ++k) {
            float4 xa = *(const float4*)&xT[k][ty * 4];
            float4 wv = *(const float4*)&ws2[k][tx * 4];
            float xr[4] = {xa.x, xa.y, xa.z, xa.w};
            float wc[4] = {wv.x, wv.y, wv.z, wv.w};
#pragma unroll
            for (int r = 0; r < 4; ++r)
#pragma unroll
                for (int c = 0; c < 4; ++c) acc[r][c] += xr[r] * wc[c];
        }
    }

    const float4 asv = *(const float4*)(attS + tx * 4);
    const float4 adv = *(const float4*)(attD + tx * 4);
#pragma unroll
    for (int r = 0; r < 4; ++r) {
        int n = n0 + ty * 4 + r;
        float ts = acc[r][0] * asv.x + acc[r][1] * asv.y + acc[r][2] * asv.z + acc[r][3] * asv.w;
        float td = acc[r][0] * adv.x + acc[r][1] * adv.y + acc[r][2] * adv.z + acc[r][3] * adv.w;
        ts += __shfl_xor(ts, 1); td += __shfl_xor(td, 1);
        ts += __shfl_xor(ts, 2); td += __shfl_xor(td, 2);
        ts += __shfl_xor(ts, 4); td += __shfl_xor(td, 4);
        ts += __shfl_xor(ts, 8); td += __shfl_xor(td, 8);
        if (n < N) {
            *(__half2*)&hx2h[(size_t)n * D2N + tx * 4]     = __floats2half2_rn(acc[r][0], acc[r][1]);
            *(__half2*)&hx2h[(size_t)n * D2N + tx * 4 + 2] = __floats2half2_rn(acc[r][2], acc[r][3]);
            if (tx == 0) { as2[n] = ts; ad2[n] = td; }
        }
    }
}

// ---------------- layer 2 aggregate: no-max softmax, fp16 gather, last num_new nodes ----------------
__global__ void agg2_kernel(const int* __restrict__ edge_src, const int* __restrict__ offsets,
                            const float* __restrict__ as2, const float* __restrict__ ad2,
                            const __half* __restrict__ hx2h, const float* __restrict__ b2,
                            float* __restrict__ out, int N, int num_new) {
    __shared__ int   ssh[4][64];
    __shared__ float esh[4][64];
    int wid  = threadIdx.x >> 6;
    int w    = (blockIdx.x * blockDim.x + threadIdx.x) >> 6;
    int lane = threadIdx.x & 63;
    if (w >= num_new) return;
    int n = N - num_new + w;
    float adn = ad2[n];
    int beg = offsets[n], end = offsets[n + 1];

    float den = 0.f, acc = 0.f;
    for (int cb = beg; cb < end; cb += 64) {
        int j = cb + lane;
        bool valid = j < end;
        int s = valid ? edge_src[j] : 0;
        float e = 0.f;
        if (valid) {
            float v = as2[s] + adn;
            v = v > 0.f ? v : 0.2f * v;
            e = __expf(v);
            den += e;
        }
        ssh[wid][lane] = s;
        esh[wid][lane] = e;

        int cnt = min(64, end - cb);
#pragma unroll 4
        for (int jj = 0; jj < cnt; ++jj) {
            int   sj = ssh[wid][jj];
            float wj = esh[wid][jj];
            acc += wj * __half2float(hx2h[(size_t)sj * D2N + lane]);
        }
    }
#pragma unroll
    for (int off = 32; off > 0; off >>= 1) den += __shfl_xor(den, off, 64);
    out[(size_t)w * D2N + lane] = acc / (den + 1e-16f) + b2[lane];
}

// ---------------- launch ----------------
extern "C" void kernel_launch(void* const* d_in, const int* in_sizes, int n_in,
                              void* d_out, int out_size, void* d_ws, size_t ws_size,
                              hipStream_t stream) {
    const float* x      = (const float*)d_in[0];
    const int*   src    = (const int*)d_in[1];
    const int*   dst    = (const int*)d_in[2];
    const float* W1     = (const float*)d_in[3];
    const float* attS1  = (const float*)d_in[4];
    const float* attD1  = (const float*)d_in[5];
    const float* b1     = (const float*)d_in[6];
    const float* W2     = (const float*)d_in[7];
    const float* attS2  = (const float*)d_in[8];
    const float* attD2  = (const float*)d_in[9];
    const float* b2     = (const float*)d_in[10];

    const int N = in_sizes[0] / F_IN;   // 50000
    const int E = in_sizes[1];          // 1000000
    const int num_new = out_size / D2N; // 10000
    const int ngemm  = (N + 31) / 32;                     // 1563
    const int nbuk   = (N + 255) >> 8;                    // 196
    const int M      = nbuk * NBLK_P;                     // 50176
    const int ntilesM = (M + SCAN_TILE - 1) / SCAN_TILE;  // 98
    const int chunk  = (E + NBLK_P - 1) / NBLK_P;         // 3907

    // workspace carve-up
    __half* hx1h = (__half*)d_ws;                        // N*128 halves
    __half* x1h  = hx1h + (size_t)N * C1;                // N*128 halves
    __half* hx2h = x1h  + (size_t)N * C1;                // N*64 halves
    float* as1 = (float*)(hx2h + (size_t)N * D2N);       // N*4
    float* ad1 = as1 + (size_t)N * H1N;                  // N*4
    float* as2 = ad1 + (size_t)N * H1N;                  // N
    float* ad2 = as2 + N;                                // N
    int* bcounts  = (int*)(ad2 + N);                     // M
    int* bbase    = bcounts + M;                         // M+1
    int* offsets  = bbase + M + 1;                       // N+1
    int* tilesums = offsets + N + 1;                     // 256
    int* tilebase = tilesums + 256;                      // 256
    int* edge_src = tilebase + 256;                      // E
    int2* pedge   = (int2*)(edge_src + E);               // E int2
    __half* W1T   = (__half*)(pedge + E);                // 128*256 halves

    float* out = (float*)d_out;

    hipLaunchKernelGGL(prep_kernel, dim3(C1 + NBLK_P), dim3(256), 0, stream,
                       W1, W1T, dst, bcounts, E, chunk, nbuk);
    hipLaunchKernelGGL(scan_partial, dim3(ntilesM), dim3(SCAN_T), 0, stream, bcounts, tilesums, M);
    hipLaunchKernelGGL(scan_tops, dim3(1), dim3(SCAN_T), 0, stream, tilesums, tilebase, ntilesM);
    hipLaunchKernelGGL(scan_final, dim3(ntilesM), dim3(SCAN_T), 0, stream,
                       bcounts, tilebase, bbase, M, E);
    hipLaunchKernelGGL(gemm1_scatter_kernel, dim3(ngemm + NBLK_P), dim3(256), 0, stream,
                       x, W1T, attS1, attD1, hx1h, as1, ad1, N,
                       src, dst, bbase, pedge, E, chunk, nbuk, ngemm);
    hipLaunchKernelGGL(part_csr, dim3(nbuk), dim3(1024), 0, stream,
                       pedge, bbase, offsets, edge_src, N, E, nbuk);
    hipLaunchKernelGGL(agg1_kernel, dim3((N + 3) / 4), dim3(256), 0, stream,
                       edge_src, offsets, as1, ad1, hx1h, b1, x1h, N);
    hipLaunchKernelGGL(gemm2_kernel, dim3((N + 63) / 64), dim3(256), 0, stream,
                       x1h, W2, attS2, attD2, hx2h, as2, ad2, N);
    hipLaunchKernelGGL(agg2_kernel, dim3((num_new + 3) / 4), dim3(256), 0, stream,
                       edge_src, offsets, as2, ad2, hx2h, b2, out, N, num_new);
}

// Round 25
// 138.723 us; speedup vs baseline: 1.1318x; 1.0049x over previous
//
#include <hip/hip_runtime.h>
#include <hip/hip_fp16.h>
#include <math.h>

#define F_IN   256
#define C1     128   // H1*D1
#define H1N    4
#define D2N    64

#define SCAN_T    256
#define SCAN_TILE 512   // 2 elements per thread

#define BK2 32          // gemm2 K-tile

#define NBLK_P 256      // partition blocks
#define NBUK_MAX 256    // max coarse buckets (dst >> 8)

typedef __attribute__((ext_vector_type(8))) _Float16 f16x8;
typedef __attribute__((ext_vector_type(4))) float    f32x4;

// ---------------- prep: W1 transpose (blocks<128) + bucket histogram (rest) ----------------
__global__ void prep_kernel(const float* __restrict__ W1, __half* __restrict__ W1T,
                            const int* __restrict__ dst, int* __restrict__ bcounts,
                            int E, int chunk, int nbuk) {
    if ((int)blockIdx.x < C1) {
        int c = blockIdx.x;
        for (int k = threadIdx.x; k < F_IN; k += blockDim.x)
            W1T[(size_t)c * F_IN + k] = __float2half(W1[(size_t)k * C1 + c]);
        return;
    }
    __shared__ int h[NBUK_MAX];
    int b = blockIdx.x - C1;                  // 0..NBLK_P-1
    for (int t = threadIdx.x; t < nbuk; t += blockDim.x) h[t] = 0;
    __syncthreads();
    int lo = b * chunk, hi = min(lo + chunk, E);
    for (int i = lo + threadIdx.x; i < hi; i += blockDim.x)
        atomicAdd(&h[dst[i] >> 8], 1);                 // LDS atomic
    __syncthreads();
    for (int t = threadIdx.x; t < nbuk; t += blockDim.x)
        bcounts[(size_t)t * NBLK_P + b] = h[t];
}

// ---------------- fused: layer-1 MFMA GEMM BM=32 (blocks < ngemm) + edge partition ----------------
// pedge packed: (src << 8) | (dst & 255) — src < 2^24, in-bucket offset in 8 bits.
// Halves the scatter's random-write and part_csr's re-read traffic.
__global__ __launch_bounds__(256) void gemm1_scatter_kernel(
        const float* __restrict__ x, const __half* __restrict__ W1T,
        const float* __restrict__ attS, const float* __restrict__ attD,
        __half* __restrict__ hx1h, float* __restrict__ as1, float* __restrict__ ad1,
        int N,
        const int* __restrict__ src, const int* __restrict__ dst,
        const int* __restrict__ bbase, unsigned int* __restrict__ pedge,
        int E, int chunk, int nbuk, int ngemm) {
    if ((int)blockIdx.x >= ngemm) {
        __shared__ int cur[NBUK_MAX];
        int b = blockIdx.x - ngemm;           // 0..NBLK_P-1
        for (int t = threadIdx.x; t < nbuk; t += blockDim.x)
            cur[t] = bbase[(size_t)t * NBLK_P + b];
        __syncthreads();
        int lo = b * chunk, hi = min(lo + chunk, E);
        for (int i = lo + threadIdx.x; i < hi; i += blockDim.x) {
            int d = dst[i];
            int p = atomicAdd(&cur[d >> 8], 1);        // LDS atomic
            pedge[p] = ((unsigned int)src[i] << 8) | (unsigned int)(d & 255);
        }
        return;
    }

    __shared__ __half xh[32][40];   // 80B row stride: 16B-aligned, 2-way banks max

    int tid = threadIdx.x;
    int wv  = tid >> 6;             // wave 0..3
    int l   = tid & 63;
    int n0  = blockIdx.x * 32;

    f32x4 acc[4];
#pragma unroll
    for (int t = 0; t < 4; ++t) acc[t] = (f32x4){0.f, 0.f, 0.f, 0.f};

    int srow = tid >> 3;                  // 0..31
    int skg  = (tid & 7) * 4;             // 0,4,...,28
    int xrow = n0 + srow; if (xrow >= N) xrow = N - 1;   // clamp (stores guarded)
    const float* xptr = x + (size_t)xrow * F_IN;

    int r0 = (wv & 1) * 16;               // wave's row tile
    int c0 = (wv >> 1) * 64;              // wave's col half
    int arow = r0 + (l & 15);             // A row within block tile
    int akk  = (l >> 4) * 8;              // A k-run
    int bcol = l & 15;                    // B col within 16-col tile
    int bkk  = (l >> 4) * 8;              // B k-run

    float4 a0 = *(const float4*)(xptr + skg);   // prologue: K-step 0

    for (int s = 0; s < 8; ++s) {
        int k0 = s * 32;
        __syncthreads();                  // previous tile consumed
        __half2* dp = (__half2*)&xh[srow][skg];
        dp[0] = __floats2half2_rn(a0.x, a0.y);
        dp[1] = __floats2half2_rn(a0.z, a0.w);
        __syncthreads();
        if (s < 7)                        // prefetch next K-step
            a0 = *(const float4*)(xptr + k0 + 32 + skg);
        f16x8 af = *reinterpret_cast<const f16x8*>(&xh[arow][akk]);
#pragma unroll
        for (int t = 0; t < 4; ++t) {
            f16x8 bf = *reinterpret_cast<const f16x8*>(
                W1T + (size_t)(c0 + 16 * t + bcol) * F_IN + k0 + bkk);
            acc[t] = __builtin_amdgcn_mfma_f32_16x16x32_f16(af, bf, acc[t], 0, 0, 0);
        }
    }

    // epilogue: D layout col = l&15, row = 4*(l>>4)+r
    float aS[4], aD[4];
#pragma unroll
    for (int t = 0; t < 4; ++t) {
        aS[t] = attS[c0 + 16 * t + bcol];
        aD[t] = attD[c0 + 16 * t + bcol];
    }
    int hA = c0 >> 5;                     // first head owned by this wave (0 or 2)
#pragma unroll
    for (int r = 0; r < 4; ++r) {
        int n = n0 + r0 + 4 * (l >> 4) + r;
        float ts0 = acc[0][r] * aS[0] + acc[1][r] * aS[1];
        float td0 = acc[0][r] * aD[0] + acc[1][r] * aD[1];
        float ts1 = acc[2][r] * aS[2] + acc[3][r] * aS[3];
        float td1 = acc[2][r] * aD[2] + acc[3][r] * aD[3];
#pragma unroll
        for (int off = 1; off <= 8; off <<= 1) {
            ts0 += __shfl_xor(ts0, off, 64); td0 += __shfl_xor(td0, off, 64);
            ts1 += __shfl_xor(ts1, off, 64); td1 += __shfl_xor(td1, off, 64);
        }
        if (n < N) {
#pragma unroll
            for (int t = 0; t < 4; ++t)
                hx1h[(size_t)n * C1 + c0 + 16 * t + bcol] = __float2half(acc[t][r]);
            if (bcol == 0) {
                as1[n * H1N + hA]     = ts0; ad1[n * H1N + hA]     = td0;
                as1[n * H1N + hA + 1] = ts1; ad1[n * H1N + hA + 1] = td1;
            }
        }
    }
}

// ---------------- CSR build pass D: per-bucket fine CSR, 1024 threads/block ----------------
__global__ __launch_bounds__(1024) void part_csr(
        const unsigned int* __restrict__ pedge, const int* __restrict__ bbase,
        int* __restrict__ offsets, int* __restrict__ edge_src,
        int N, int E, int nbuk) {
    __shared__ int fcnt[256];
    __shared__ int fsc[256];
    int b   = blockIdx.x;
    int tid = threadIdx.x;
    int ebeg = bbase[(size_t)b * NBLK_P];
    int eend = (b + 1 < nbuk) ? bbase[(size_t)(b + 1) * NBLK_P] : E;
    int nbase = b << 8;
    if (tid < 256) fcnt[tid] = 0;
    __syncthreads();
    for (int i = ebeg + tid; i < eend; i += 1024)
        atomicAdd(&fcnt[pedge[i] & 255u], 1);          // LDS atomic
    __syncthreads();
    int v = 0;
    if (tid < 256) { v = fcnt[tid]; fsc[tid] = v; }
    __syncthreads();
    for (int off = 1; off < 256; off <<= 1) {
        int u = 0;
        if (tid < 256 && tid >= off) u = fsc[tid - off];
        __syncthreads();
        if (tid < 256 && tid >= off) fsc[tid] += u;
        __syncthreads();
    }
    if (tid < 256) {
        int goff = ebeg + fsc[tid] - v;                // global CSR start of node nbase+tid
        int node = nbase + tid;
        if (node < N) offsets[node] = goff;
        fcnt[tid] = goff;                              // reuse as cursor
    }
    if (b == nbuk - 1 && tid == 0) offsets[N] = E;
    __syncthreads();
    for (int i = ebeg + tid; i < eend; i += 1024) {
        unsigned int e = pedge[i];
        int p = atomicAdd(&fcnt[e & 255u], 1);         // LDS atomic
        edge_src[p] = (int)(e >> 8);
    }
}

// ---------------- scan: generic hierarchical exclusive scan ----------------
__global__ void scan_partial(const int* __restrict__ counts, int* __restrict__ tilesums, int N) {
    __shared__ int red[SCAN_T];
    int t  = threadIdx.x;
    int i0 = blockIdx.x * SCAN_TILE + 2 * t;
    int s = 0;
    if (i0     < N) s += counts[i0];
    if (i0 + 1 < N) s += counts[i0 + 1];
    red[t] = s;
    __syncthreads();
    for (int off = SCAN_T / 2; off > 0; off >>= 1) {
        if (t < off) red[t] += red[t + off];
        __syncthreads();
    }
    if (t == 0) tilesums[blockIdx.x] = red[0];
}

__global__ void scan_tops(const int* __restrict__ tilesums, int* __restrict__ tilebase, int ntiles) {
    __shared__ int sh[SCAN_T];
    int t = threadIdx.x;
    int v = (t < ntiles) ? tilesums[t] : 0;
    sh[t] = v;
    __syncthreads();
    for (int off = 1; off < SCAN_T; off <<= 1) {
        int u = (t >= off) ? sh[t - off] : 0;
        __syncthreads();
        sh[t] += u;
        __syncthreads();
    }
    tilebase[t] = sh[t] - v;
}

__global__ void scan_final(const int* __restrict__ counts, const int* __restrict__ tilebase,
                           int* __restrict__ base, int N, int E) {
    __shared__ int sh[SCAN_T];
    int t  = threadIdx.x;
    int i0 = blockIdx.x * SCAN_TILE + 2 * t;
    int a   = (i0     < N) ? counts[i0]     : 0;
    int b   = (i0 + 1 < N) ? counts[i0 + 1] : 0;
    int tot = a + b;
    sh[t] = tot;
    __syncthreads();
    for (int off = 1; off < SCAN_T; off <<= 1) {
        int u = (t >= off) ? sh[t - off] : 0;
        __syncthreads();
        sh[t] += u;
        __syncthreads();
    }
    int excl = sh[t] - tot + tilebase[blockIdx.x];
    if (i0 < N)     base[i0]     = excl;
    if (i0 + 1 < N) base[i0 + 1] = excl + a;
    if (blockIdx.x == 0 && t == 0) base[N] = E;
}

// ---------------- layer 1 aggregate: no-max softmax, fp16 gather, fp16 x1 out ----------------
__global__ void agg1_kernel(const int* __restrict__ edge_src, const int* __restrict__ offsets,
                            const float* __restrict__ as1, const float* __restrict__ ad1,
                            const __half* __restrict__ hx1h, const float* __restrict__ b1,
                            __half* __restrict__ x1h, int N) {
    __shared__ int   ssh[4][64];
    __shared__ float esh[4][64][4];
    int wid  = threadIdx.x >> 6;
    int n    = (blockIdx.x * blockDim.x + threadIdx.x) >> 6;
    int lane = threadIdx.x & 63;
    if (n >= N) return;
    int hsel = lane >> 4;                    // head of cols (2l, 2l+1)
    const float4 ad4 = *(const float4*)(ad1 + 4 * n);
    int beg = offsets[n], end = offsets[n + 1];

    float den[4] = {0.f, 0.f, 0.f, 0.f};
    float acc0 = 0.f, acc1 = 0.f;

    for (int cb = beg; cb < end; cb += 64) {
        int j = cb + lane;
        bool valid = j < end;
        int s = valid ? edge_src[j] : 0;
        float e0 = 0.f, e1 = 0.f, e2 = 0.f, e3 = 0.f;
        if (valid) {
            const float4 a4 = *(const float4*)(as1 + 4 * s);
            float v0 = a4.x + ad4.x, v1 = a4.y + ad4.y;
            float v2 = a4.z + ad4.z, v3 = a4.w + ad4.w;
            v0 = v0 > 0.f ? v0 : 0.2f * v0;
            v1 = v1 > 0.f ? v1 : 0.2f * v1;
            v2 = v2 > 0.f ? v2 : 0.2f * v2;
            v3 = v3 > 0.f ? v3 : 0.2f * v3;
            e0 = __expf(v0); e1 = __expf(v1);
            e2 = __expf(v2); e3 = __expf(v3);
            den[0] += e0; den[1] += e1; den[2] += e2; den[3] += e3;
        }
        ssh[wid][lane] = s;
        *(float4*)&esh[wid][lane][0] = make_float4(e0, e1, e2, e3);

        int cnt = min(64, end - cb);
#pragma unroll 4
        for (int jj = 0; jj < cnt; ++jj) {
            int   sj = ssh[wid][jj];
            float w  = esh[wid][jj][hsel];
            const __half2* hr = (const __half2*)(hx1h + (size_t)sj * C1);
            float2 vf = __half22float2(hr[lane]);
            acc0 += w * vf.x;
            acc1 += w * vf.y;
        }
    }

#pragma unroll
    for (int off = 32; off > 0; off >>= 1)
#pragma unroll
        for (int h = 0; h < 4; ++h) den[h] += __shfl_xor(den[h], off, 64);

    float d = lane < 16 ? den[0] : lane < 32 ? den[1] : lane < 48 ? den[2] : den[3];
    float inv = 1.f / (d + 1e-16f);
    float2 bv = *(const float2*)(b1 + 2 * lane);
    float o0 = acc0 * inv + bv.x;
    float o1 = acc1 * inv + bv.y;
    o0 = o0 > 0.f ? o0 : (__expf(o0) - 1.f);   // ELU
    o1 = o1 > 0.f ? o1 : (__expf(o1) - 1.f);
    *(__half2*)&x1h[(size_t)n * C1 + 2 * lane] = __floats2half2_rn(o0, o1);
}

// ---------------- layer 2 GEMM: hx2 = x1 @ W2 (+ logits); fp16 in, fp16 out ----------------
__global__ __launch_bounds__(256) void gemm2_kernel(
        const __half* __restrict__ x1h, const float* __restrict__ W2,
        const float* __restrict__ attS, const float* __restrict__ attD,
        __half* __restrict__ hx2h, float* __restrict__ as2, float* __restrict__ ad2,
        int N) {
    __shared__ float xT[BK2][64 + 4];
    __shared__ float ws2[BK2][D2N];

    int tid = threadIdx.x;
    int tx  = tid & 15;
    int ty  = tid >> 4;
    int n0  = blockIdx.x * 64;

    float acc[4][4];
#pragma unroll
    for (int r = 0; r < 4; ++r)
#pragma unroll
        for (int c = 0; c < 4; ++c) acc[r][c] = 0.f;

    int lr = tid >> 2;                 // 0..63
    int lk = (tid & 3) * 8;            // 0,8,16,24 (8 halves = 16B)
    int xrow = n0 + lr; if (xrow >= N) xrow = N - 1;
    const __half* xptr = x1h + (size_t)xrow * C1;
    int kw = tid >> 4;
    int cw = tx * 4;

    for (int k0 = 0; k0 < C1; k0 += BK2) {
        f16x8 a = *reinterpret_cast<const f16x8*>(xptr + k0 + lk);
        float4 w0 = *(const float4*)(W2 + (size_t)(k0 + kw     ) * D2N + cw);
        float4 w1 = *(const float4*)(W2 + (size_t)(k0 + kw + 16) * D2N + cw);
        __syncthreads();
#pragma unroll
        for (int j = 0; j < 8; ++j) xT[lk + j][lr] = (float)a[j];
        *(float4*)&ws2[kw     ][cw] = w0;
        *(float4*)&ws2[kw + 16][cw] = w1;
        __syncthreads();
#pragma unroll
        for (int k = 0; k < BK2; ++k) {
            float4 xa = *(const float4*)&xT[k][ty * 4];
            float4 wv = *(const float4*)&ws2[k][tx * 4];
            float xr[4] = {xa.x, xa.y, xa.z, xa.w};
            float wc[4] = {wv.x, wv.y, wv.z, wv.w};
#pragma unroll
            for (int r = 0; r < 4; ++r)
#pragma unroll
                for (int c = 0; c < 4; ++c) acc[r][c] += xr[r] * wc[c];
        }
    }

    const float4 asv = *(const float4*)(attS + tx * 4);
    const float4 adv = *(const float4*)(attD + tx * 4);
#pragma unroll
    for (int r = 0; r < 4; ++r) {
        int n = n0 + ty * 4 + r;
        float ts = acc[r][0] * asv.x + acc[r][1] * asv.y + acc[r][2] * asv.z + acc[r][3] * asv.w;
        float td = acc[r][0] * adv.x + acc[r][1] * adv.y + acc[r][2] * adv.z + acc[r][3] * adv.w;
        ts += __shfl_xor(ts, 1); td += __shfl_xor(td, 1);
        ts += __shfl_xor(ts, 2); td += __shfl_xor(td, 2);
        ts += __shfl_xor(ts, 4); td += __shfl_xor(td, 4);
        ts += __shfl_xor(ts, 8); td += __shfl_xor(td, 8);
        if (n < N) {
            *(__half2*)&hx2h[(size_t)n * D2N + tx * 4]     = __floats2half2_rn(acc[r][0], acc[r][1]);
            *(__half2*)&hx2h[(size_t)n * D2N + tx * 4 + 2] = __floats2half2_rn(acc[r][2], acc[r][3]);
            if (tx == 0) { as2[n] = ts; ad2[n] = td; }
        }
    }
}

// ---------------- layer 2 aggregate: no-max softmax, fp16 gather, last num_new nodes ----------------
__global__ void agg2_kernel(const int* __restrict__ edge_src, const int* __restrict__ offsets,
                            const float* __restrict__ as2, const float* __restrict__ ad2,
                            const __half* __restrict__ hx2h, const float* __restrict__ b2,
                            float* __restrict__ out, int N, int num_new) {
    __shared__ int   ssh[4][64];
    __shared__ float esh[4][64];
    int wid  = threadIdx.x >> 6;
    int w    = (blockIdx.x * blockDim.x + threadIdx.x) >> 6;
    int lane = threadIdx.x & 63;
    if (w >= num_new) return;
    int n = N - num_new + w;
    float adn = ad2[n];
    int beg = offsets[n], end = offsets[n + 1];

    float den = 0.f, acc = 0.f;
    for (int cb = beg; cb < end; cb += 64) {
        int j = cb + lane;
        bool valid = j < end;
        int s = valid ? edge_src[j] : 0;
        float e = 0.f;
        if (valid) {
            float v = as2[s] + adn;
            v = v > 0.f ? v : 0.2f * v;
            e = __expf(v);
            den += e;
        }
        ssh[wid][lane] = s;
        esh[wid][lane] = e;

        int cnt = min(64, end - cb);
#pragma unroll 4
        for (int jj = 0; jj < cnt; ++jj) {
            int   sj = ssh[wid][jj];
            float wj = esh[wid][jj];
            acc += wj * __half2float(hx2h[(size_t)sj * D2N + lane]);
        }
    }
#pragma unroll
    for (int off = 32; off > 0; off >>= 1) den += __shfl_xor(den, off, 64);
    out[(size_t)w * D2N + lane] = acc / (den + 1e-16f) + b2[lane];
}

// ---------------- launch ----------------
extern "C" void kernel_launch(void* const* d_in, const int* in_sizes, int n_in,
                              void* d_out, int out_size, void* d_ws, size_t ws_size,
                              hipStream_t stream) {
    const float* x      = (const float*)d_in[0];
    const int*   src    = (const int*)d_in[1];
    const int*   dst    = (const int*)d_in[2];
    const float* W1     = (const float*)d_in[3];
    const float* attS1  = (const float*)d_in[4];
    const float* attD1  = (const float*)d_in[5];
    const float* b1     = (const float*)d_in[6];
    const float* W2     = (const float*)d_in[7];
    const float* attS2  = (const float*)d_in[8];
    const float* attD2  = (const float*)d_in[9];
    const float* b2     = (const float*)d_in[10];

    const int N = in_sizes[0] / F_IN;   // 50000
    const int E = in_sizes[1];          // 1000000
    const int num_new = out_size / D2N; // 10000
    const int ngemm  = (N + 31) / 32;                     // 1563
    const int nbuk   = (N + 255) >> 8;                    // 196
    const int M      = nbuk * NBLK_P;                     // 50176
    const int ntilesM = (M + SCAN_TILE - 1) / SCAN_TILE;  // 98
    const int chunk  = (E + NBLK_P - 1) / NBLK_P;         // 3907

    // workspace carve-up
    __half* hx1h = (__half*)d_ws;                        // N*128 halves
    __half* x1h  = hx1h + (size_t)N * C1;                // N*128 halves
    __half* hx2h = x1h  + (size_t)N * C1;                // N*64 halves
    float* as1 = (float*)(hx2h + (size_t)N * D2N);       // N*4
    float* ad1 = as1 + (size_t)N * H1N;                  // N*4
    float* as2 = ad1 + (size_t)N * H1N;                  // N
    float* ad2 = as2 + N;                                // N
    int* bcounts  = (int*)(ad2 + N);                     // M
    int* bbase    = bcounts + M;                         // M+1
    int* offsets  = bbase + M + 1;                       // N+1
    int* tilesums = offsets + N + 1;                     // 256
    int* tilebase = tilesums + 256;                      // 256
    int* edge_src = tilebase + 256;                      // E
    unsigned int* pedge = (unsigned int*)(edge_src + E); // E u32 (packed src<<8 | d&255)
    __half* W1T   = (__half*)(pedge + E);                // 128*256 halves

    float* out = (float*)d_out;

    hipLaunchKernelGGL(prep_kernel, dim3(C1 + NBLK_P), dim3(256), 0, stream,
                       W1, W1T, dst, bcounts, E, chunk, nbuk);
    hipLaunchKernelGGL(scan_partial, dim3(ntilesM), dim3(SCAN_T), 0, stream, bcounts, tilesums, M);
    hipLaunchKernelGGL(scan_tops, dim3(1), dim3(SCAN_T), 0, stream, tilesums, tilebase, ntilesM);
    hipLaunchKernelGGL(scan_final, dim3(ntilesM), dim3(SCAN_T), 0, stream,
                       bcounts, tilebase, bbase, M, E);
    hipLaunchKernelGGL(gemm1_scatter_kernel, dim3(ngemm + NBLK_P), dim3(256), 0, stream,
                       x, W1T, attS1, attD1, hx1h, as1, ad1, N,
                       src, dst, bbase, pedge, E, chunk, nbuk, ngemm);
    hipLaunchKernelGGL(part_csr, dim3(nbuk), dim3(1024), 0, stream,
                       pedge, bbase, offsets, edge_src, N, E, nbuk);
    hipLaunchKernelGGL(agg1_kernel, dim3((N + 3) / 4), dim3(256), 0, stream,
                       edge_src, offsets, as1, ad1, hx1h, b1, x1h, N);
    hipLaunchKernelGGL(gemm2_kernel, dim3((N + 63) / 64), dim3(256), 0, stream,
                       x1h, W2, attS2, attD2, hx2h, as2, ad2, N);
    hipLaunchKernelGGL(agg2_kernel, dim3((num_new + 3) / 4), dim3(256), 0, stream,
                       edge_src, offsets, as2, ad2, hx2h, b2, out, N, num_new);
}